// Round 10
// baseline (3132.248 us; speedup 1.0000x reference)
//
#include <hip/hip_runtime.h>
#include <stdint.h>

#define BSIZE 1024
#define DIM   16384
#define HID   1024
#define TAIL  ((size_t)960 * DIM)   /* two-phase fallback: h region start in d_out */
#define SPLITK 8
#define KC     (DIM / SPLITK)       /* 2048 */
#define NT    1024                  /* wide row kernel threads (R9 fallback) */
#define SV    (DIM / NT)
#define GTN   (1u << 23)            /* gumbel table entries (23 mantissa bits) */

// ---------------- threefry2x32 (JAX-compatible, 20 rounds) ----------------
__device__ __forceinline__ void tf2x32(uint32_t k0, uint32_t k1,
                                       uint32_t x0, uint32_t x1,
                                       uint32_t& o0, uint32_t& o1) {
  const uint32_t ks2 = k0 ^ k1 ^ 0x1BD11BDAu;
#define TFR(r) { x0 += x1; x1 = (x1 << r) | (x1 >> (32 - r)); x1 ^= x0; }
  x0 += k0; x1 += k1;
  TFR(13) TFR(15) TFR(26) TFR(6)
  x0 += k1;  x1 += ks2 + 1u;
  TFR(17) TFR(29) TFR(16) TFR(24)
  x0 += ks2; x1 += k0 + 2u;
  TFR(13) TFR(15) TFR(26) TFR(6)
  x0 += k0;  x1 += k1 + 3u;
  TFR(17) TFR(29) TFR(16) TFR(24)
  x0 += k1;  x1 += ks2 + 4u;
  TFR(13) TFR(15) TFR(26) TFR(6)
  x0 += ks2; x1 += k0 + 5u;
#undef TFR
  o0 = x0; o1 = x1;
}

__device__ __forceinline__ float bits_to_unit_float(uint32_t bits) {
  return __uint_as_float((bits >> 9) | 0x3f800000u) - 1.0f;
}

__device__ __forceinline__ float bits_to_gumbel(uint32_t bits) {
  float u = bits_to_unit_float(bits);
  if (u == 0.0f) u = 1.1754943508222875e-38f;   // minval = finfo(f32).tiny
  float l1 = (float)log((double)u);
  float nl1 = -l1;
  float l2 = (float)log((double)nl1);
  return -l2;
}

__device__ __forceinline__ double softplus_d(double z) {
  return (z > 0.0) ? (z + log1p(exp(-z))) : log1p(exp(z));
}

// ------- K0: fill gumbel table — gt[m] = bits_to_gumbel(m<<9), bit-identical -------
__global__ __launch_bounds__(256) void fill_gtable_kernel(float* __restrict__ gt) {
  const uint32_t m = blockIdx.x * 256 + threadIdx.x;   // [0, 2^23)
  gt[m] = bits_to_gumbel(m << 9);
}

// ------- K1: split-K GEMM  P[s] = x[:, sKC:(s+1)KC] @ W[sKC:...]  (128x128) -------
__global__ __launch_bounds__(256) void gemm_h_split_kernel(
    const float* __restrict__ x, const float* __restrict__ W,
    float* __restrict__ P) {
  __shared__ float Al[32][128];
  __shared__ float Bl[32][128];
  const int tid = threadIdx.x;
  const int n0 = blockIdx.x * 128;
  const int m0 = blockIdx.y * 128;
  const int s  = blockIdx.z;
  const int arow = tid >> 1, akof = (tid & 1) * 16;
  const int brow = tid >> 3, bcol = (tid & 7) * 16;
  const int ty = tid >> 4, tx = tid & 15;

  float acc[8][8];
  for (int i = 0; i < 8; ++i)
    for (int j = 0; j < 8; ++j) acc[i][j] = 0.0f;

  for (int kt = 0; kt < KC / 32; ++kt) {
    const int k0 = s * KC + kt * 32;
    const float* ap = x + (size_t)(m0 + arow) * DIM + k0 + akof;
    float4 av0 = *(const float4*)(ap + 0);
    float4 av1 = *(const float4*)(ap + 4);
    float4 av2 = *(const float4*)(ap + 8);
    float4 av3 = *(const float4*)(ap + 12);
    const float* bp = W + (size_t)(k0 + brow) * HID + n0 + bcol;
    float4 bv0 = *(const float4*)(bp + 0);
    float4 bv1 = *(const float4*)(bp + 4);
    float4 bv2 = *(const float4*)(bp + 8);
    float4 bv3 = *(const float4*)(bp + 12);
    __syncthreads();
    {
      float ta[16] = {av0.x,av0.y,av0.z,av0.w, av1.x,av1.y,av1.z,av1.w,
                      av2.x,av2.y,av2.z,av2.w, av3.x,av3.y,av3.z,av3.w};
      for (int e = 0; e < 16; ++e) Al[akof + e][arow] = ta[e];
    }
    *(float4*)&Bl[brow][bcol + 0]  = bv0;
    *(float4*)&Bl[brow][bcol + 4]  = bv1;
    *(float4*)&Bl[brow][bcol + 8]  = bv2;
    *(float4*)&Bl[brow][bcol + 12] = bv3;
    __syncthreads();
#pragma unroll 4
    for (int k = 0; k < 32; ++k) {
      const float4 a0 = *(const float4*)&Al[k][ty * 8];
      const float4 a1 = *(const float4*)&Al[k][ty * 8 + 4];
      const float4 b0 = *(const float4*)&Bl[k][tx * 8];
      const float4 b1 = *(const float4*)&Bl[k][tx * 8 + 4];
      const float a[8]  = {a0.x,a0.y,a0.z,a0.w, a1.x,a1.y,a1.z,a1.w};
      const float bb[8] = {b0.x,b0.y,b0.z,b0.w, b1.x,b1.y,b1.z,b1.w};
      for (int i = 0; i < 8; ++i)
        for (int j = 0; j < 8; ++j)
          acc[i][j] = fmaf(a[i], bb[j], acc[i][j]);
    }
  }
  float* Cp = P + (size_t)s * (BSIZE * HID);
  for (int i = 0; i < 8; ++i) {
    const int gm = m0 + ty * 8 + i;
    float4 w0 = {acc[i][0], acc[i][1], acc[i][2], acc[i][3]};
    float4 w1 = {acc[i][4], acc[i][5], acc[i][6], acc[i][7]};
    *(float4*)(Cp + (size_t)gm * HID + n0 + tx * 8 + 0) = w0;
    *(float4*)(Cp + (size_t)gm * HID + n0 + tx * 8 + 4) = w1;
  }
}

// ------- K1r: h = sum_s P[s] + bh (fixed order) -> hbuf; optional sig -------
__global__ __launch_bounds__(256) void reduce_h_sig_kernel(
    const float* __restrict__ P, const float* __restrict__ bh,
    float* __restrict__ hbuf, float* __restrict__ sig /* may be null */) {
  const int i = blockIdx.x * 256 + threadIdx.x;   // float4 idx, 262144 total
  float4 a = ((const float4*)P)[i];
  for (int s = 1; s < SPLITK; ++s) {
    float4 p = ((const float4*)P)[(size_t)s * (BSIZE * HID / 4) + i];
    a.x += p.x; a.y += p.y; a.z += p.z; a.w += p.w;
  }
  float4 bv = ((const float4*)bh)[i & (HID / 4 - 1)];
  float4 h;
  h.x = a.x + bv.x; h.y = a.y + bv.y; h.z = a.z + bv.z; h.w = a.w + bv.w;
  ((float4*)hbuf)[i] = h;
  if (sig) {
    float4 sg;
    sg.x = (float)(1.0 / (1.0 + exp(-(double)h.x)));
    sg.y = (float)(1.0 / (1.0 + exp(-(double)h.y)));
    sg.z = (float)(1.0 / (1.0 + exp(-(double)h.z)));
    sg.w = (float)(1.0 / (1.0 + exp(-(double)h.w)));
    ((float4*)sig)[i] = sg;
  }
}

// ------- K1b: stash h rows 960..1023 into d_ws (two-phase fallback) -------
__global__ __launch_bounds__(256) void copy_stash_kernel(
    const float* __restrict__ src, float* __restrict__ dst) {
  const int i = blockIdx.x * 256 + threadIdx.x;
  ((float4*)dst)[i] = ((const float4*)src)[i];
}

// -- K2 (fallback, R4-exact): s = (1-2x)*(sigmoid(h) @ W^T + c)*0.5 --
__global__ __launch_bounds__(256) void gemm2_kernel(
    const float* __restrict__ h_src, const float* __restrict__ W,
    const float* __restrict__ c, const float* __restrict__ x,
    float* __restrict__ s_dst, int m_start) {
  __shared__ float Al[32][64];
  __shared__ float Bl[32][128];
  const int tid = threadIdx.x;
  const int m0l = blockIdx.x * 64;
  const int n0  = blockIdx.y * 128;
  const int arow = tid >> 2, ak = (tid & 3) * 8;
  const int nrow = tid >> 1, kof = (tid & 1) * 16;
  const int ty = tid >> 4, tx = tid & 15;

  float acc[4][8];
  for (int i = 0; i < 4; ++i)
    for (int j = 0; j < 8; ++j) acc[i][j] = 0.0f;

  for (int kt = 0; kt < HID / 32; ++kt) {
    const int k0 = kt * 32;
    const float* ap = h_src + (size_t)(m0l + arow) * HID + k0 + ak;
    float4 av0 = *(const float4*)(ap + 0);
    float4 av1 = *(const float4*)(ap + 4);
    const float* bp = W + (size_t)(n0 + nrow) * HID + k0 + kof;
    float4 bv0 = *(const float4*)(bp + 0);
    float4 bv1 = *(const float4*)(bp + 4);
    float4 bv2 = *(const float4*)(bp + 8);
    float4 bv3 = *(const float4*)(bp + 12);
    __syncthreads();
    {
      float ta[8] = {av0.x, av0.y, av0.z, av0.w, av1.x, av1.y, av1.z, av1.w};
      for (int e = 0; e < 8; ++e)
        Al[ak + e][arow] = (float)(1.0 / (1.0 + exp(-(double)ta[e])));
      float tb[16] = {bv0.x,bv0.y,bv0.z,bv0.w, bv1.x,bv1.y,bv1.z,bv1.w,
                      bv2.x,bv2.y,bv2.z,bv2.w, bv3.x,bv3.y,bv3.z,bv3.w};
      for (int e = 0; e < 16; ++e) Bl[kof + e][nrow] = tb[e];
    }
    __syncthreads();
#pragma unroll 4
    for (int k = 0; k < 32; ++k) {
      const float4 a4 = *(const float4*)&Al[k][ty * 4];
      const float4 b0 = *(const float4*)&Bl[k][tx * 8];
      const float4 b1 = *(const float4*)&Bl[k][tx * 8 + 4];
      const float a[4]  = {a4.x, a4.y, a4.z, a4.w};
      const float bb[8] = {b0.x,b0.y,b0.z,b0.w, b1.x,b1.y,b1.z,b1.w};
      for (int i = 0; i < 4; ++i)
        for (int j = 0; j < 8; ++j)
          acc[i][j] = fmaf(a[i], bb[j], acc[i][j]);
    }
  }
  for (int i = 0; i < 4; ++i) {
    const int gml = m0l + ty * 4 + i;
    const size_t xoff = (size_t)(m_start + gml) * DIM + n0 + tx * 8;
    const size_t soff = (size_t)gml * DIM + n0 + tx * 8;
    for (int q = 0; q < 2; ++q) {
      float4 xv = *(const float4*)(x + xoff + q * 4);
      float4 cv = *(const float4*)(c + n0 + tx * 8 + q * 4);
      float g0 = acc[i][q * 4 + 0] + cv.x;
      float g1 = acc[i][q * 4 + 1] + cv.y;
      float g2 = acc[i][q * 4 + 2] + cv.z;
      float g3 = acc[i][q * 4 + 3] + cv.w;
      float4 sv;
      sv.x = ((xv.x == 1.0f) ? -g0 : g0) * 0.5f;
      sv.y = ((xv.y == 1.0f) ? -g1 : g1) * 0.5f;
      sv.z = ((xv.z == 1.0f) ? -g2 : g2) * 0.5f;
      sv.w = ((xv.w == 1.0f) ? -g3 : g3) * 0.5f;
      *(float4*)(s_dst + soff + q * 4) = sv;
    }
  }
}

// -- K2s (two-phase): A = precomputed sig, 64x128 tiles --
__global__ __launch_bounds__(256) void gemm2_sig_kernel(
    const float* __restrict__ sig_src, const float* __restrict__ W,
    const float* __restrict__ c, const float* __restrict__ x,
    float* __restrict__ s_dst, int m_start) {
  __shared__ float Al[32][64];
  __shared__ float Bl[32][128];
  const int tid = threadIdx.x;
  const int m0l = blockIdx.x * 64;
  const int n0  = blockIdx.y * 128;
  const int arow = tid >> 2, ak = (tid & 3) * 8;
  const int nrow = tid >> 1, kof = (tid & 1) * 16;
  const int ty = tid >> 4, tx = tid & 15;

  float acc[4][8];
  for (int i = 0; i < 4; ++i)
    for (int j = 0; j < 8; ++j) acc[i][j] = 0.0f;

  for (int kt = 0; kt < HID / 32; ++kt) {
    const int k0 = kt * 32;
    const float* ap = sig_src + (size_t)(m0l + arow) * HID + k0 + ak;
    float4 av0 = *(const float4*)(ap + 0);
    float4 av1 = *(const float4*)(ap + 4);
    const float* bp = W + (size_t)(n0 + nrow) * HID + k0 + kof;
    float4 bv0 = *(const float4*)(bp + 0);
    float4 bv1 = *(const float4*)(bp + 4);
    float4 bv2 = *(const float4*)(bp + 8);
    float4 bv3 = *(const float4*)(bp + 12);
    __syncthreads();
    {
      float ta[8] = {av0.x, av0.y, av0.z, av0.w, av1.x, av1.y, av1.z, av1.w};
      for (int e = 0; e < 8; ++e) Al[ak + e][arow] = ta[e];
      float tb[16] = {bv0.x,bv0.y,bv0.z,bv0.w, bv1.x,bv1.y,bv1.z,bv1.w,
                      bv2.x,bv2.y,bv2.z,bv2.w, bv3.x,bv3.y,bv3.z,bv3.w};
      for (int e = 0; e < 16; ++e) Bl[kof + e][nrow] = tb[e];
    }
    __syncthreads();
#pragma unroll 4
    for (int k = 0; k < 32; ++k) {
      const float4 a4 = *(const float4*)&Al[k][ty * 4];
      const float4 b0 = *(const float4*)&Bl[k][tx * 8];
      const float4 b1 = *(const float4*)&Bl[k][tx * 8 + 4];
      const float a[4]  = {a4.x, a4.y, a4.z, a4.w};
      const float bb[8] = {b0.x,b0.y,b0.z,b0.w, b1.x,b1.y,b1.z,b1.w};
      for (int i = 0; i < 4; ++i)
        for (int j = 0; j < 8; ++j)
          acc[i][j] = fmaf(a[i], bb[j], acc[i][j]);
    }
  }
  for (int i = 0; i < 4; ++i) {
    const int gml = m0l + ty * 4 + i;
    const size_t xoff = (size_t)(m_start + gml) * DIM + n0 + tx * 8;
    const size_t soff = (size_t)gml * DIM + n0 + tx * 8;
    for (int q = 0; q < 2; ++q) {
      float4 xv = *(const float4*)(x + xoff + q * 4);
      float4 cv = *(const float4*)(c + n0 + tx * 8 + q * 4);
      float g0 = acc[i][q * 4 + 0] + cv.x;
      float g1 = acc[i][q * 4 + 1] + cv.y;
      float g2 = acc[i][q * 4 + 2] + cv.z;
      float g3 = acc[i][q * 4 + 3] + cv.w;
      float4 sv;
      sv.x = ((xv.x == 1.0f) ? -g0 : g0) * 0.5f;
      sv.y = ((xv.y == 1.0f) ? -g1 : g1) * 0.5f;
      sv.z = ((xv.z == 1.0f) ? -g2 : g2) * 0.5f;
      sv.w = ((xv.w == 1.0f) ? -g3 : g3) * 0.5f;
      *(float4*)(s_dst + soff + q * 4) = sv;
    }
  }
}

// -- K2s128 (single-phase): A = sig, 128x128 tiles --
__global__ __launch_bounds__(256) void gemm2_sig128_kernel(
    const float* __restrict__ sig_src, const float* __restrict__ W,
    const float* __restrict__ c, const float* __restrict__ x,
    float* __restrict__ s_dst) {
  __shared__ float Al[32][128];
  __shared__ float Bl[32][128];
  const int tid = threadIdx.x;
  const int m0 = blockIdx.x * 128;
  const int n0 = blockIdx.y * 128;
  const int row2 = tid >> 1, kof = (tid & 1) * 16;
  const int ty = tid >> 4, tx = tid & 15;

  float acc[8][8];
  for (int i = 0; i < 8; ++i)
    for (int j = 0; j < 8; ++j) acc[i][j] = 0.0f;

  for (int kt = 0; kt < HID / 32; ++kt) {
    const int k0 = kt * 32;
    const float* ap = sig_src + (size_t)(m0 + row2) * HID + k0 + kof;
    float4 av0 = *(const float4*)(ap + 0);
    float4 av1 = *(const float4*)(ap + 4);
    float4 av2 = *(const float4*)(ap + 8);
    float4 av3 = *(const float4*)(ap + 12);
    const float* bp = W + (size_t)(n0 + row2) * HID + k0 + kof;
    float4 bv0 = *(const float4*)(bp + 0);
    float4 bv1 = *(const float4*)(bp + 4);
    float4 bv2 = *(const float4*)(bp + 8);
    float4 bv3 = *(const float4*)(bp + 12);
    __syncthreads();
    {
      float ta[16] = {av0.x,av0.y,av0.z,av0.w, av1.x,av1.y,av1.z,av1.w,
                      av2.x,av2.y,av2.z,av2.w, av3.x,av3.y,av3.z,av3.w};
      float tb[16] = {bv0.x,bv0.y,bv0.z,bv0.w, bv1.x,bv1.y,bv1.z,bv1.w,
                      bv2.x,bv2.y,bv2.z,bv2.w, bv3.x,bv3.y,bv3.z,bv3.w};
      for (int e = 0; e < 16; ++e) { Al[kof + e][row2] = ta[e]; Bl[kof + e][row2] = tb[e]; }
    }
    __syncthreads();
#pragma unroll 4
    for (int k = 0; k < 32; ++k) {
      const float4 a0 = *(const float4*)&Al[k][ty * 8];
      const float4 a1 = *(const float4*)&Al[k][ty * 8 + 4];
      const float4 b0 = *(const float4*)&Bl[k][tx * 8];
      const float4 b1 = *(const float4*)&Bl[k][tx * 8 + 4];
      const float a[8]  = {a0.x,a0.y,a0.z,a0.w, a1.x,a1.y,a1.z,a1.w};
      const float bb[8] = {b0.x,b0.y,b0.z,b0.w, b1.x,b1.y,b1.z,b1.w};
      for (int i = 0; i < 8; ++i)
        for (int j = 0; j < 8; ++j)
          acc[i][j] = fmaf(a[i], bb[j], acc[i][j]);
    }
  }
  for (int i = 0; i < 8; ++i) {
    const int gm = m0 + ty * 8 + i;
    const size_t rowoff = (size_t)gm * DIM + n0 + tx * 8;
    for (int q = 0; q < 2; ++q) {
      float4 xv = *(const float4*)(x + rowoff + q * 4);
      float4 cv = *(const float4*)(c + n0 + tx * 8 + q * 4);
      float g0 = acc[i][q * 4 + 0] + cv.x;
      float g1 = acc[i][q * 4 + 1] + cv.y;
      float g2 = acc[i][q * 4 + 2] + cv.z;
      float g3 = acc[i][q * 4 + 3] + cv.w;
      float4 sv;
      sv.x = ((xv.x == 1.0f) ? -g0 : g0) * 0.5f;
      sv.y = ((xv.y == 1.0f) ? -g1 : g1) * 0.5f;
      sv.z = ((xv.z == 1.0f) ? -g2 : g2) * 0.5f;
      sv.w = ((xv.w == 1.0f) ? -g3 : g3) * 0.5f;
      *(float4*)(s_dst + rowoff + q * 4) = sv;
    }
  }
}

// ------- K3t (table path): green 512-thread row kernel, t-loop gumbels
// replaced by table lookups (bit-identical values by construction). -------
__global__ __launch_bounds__(512) void row_kernel_t(
    const float* __restrict__ x, const float* __restrict__ W,
    const float* __restrict__ c, const int* __restrict__ radius,
    const float* __restrict__ h_base,   // + b*HID
    const float* __restrict__ s_base,   // + b*DIM
    const float* __restrict__ gt,       // gumbel table [2^23]
    float* __restrict__ out) {
  const int b = blockIdx.x;
  const int tid = threadIdx.x;

  __shared__ float  red_v[8];
  __shared__ int    red_i[8];
  __shared__ double red_d[8];
  __shared__ int    diff[16];
  __shared__ float  sgn_sh[16];
  __shared__ float  sflip[16];
  __shared__ int    diff_cnt;
  __shared__ int    accept_flag;

  if (tid == 0) diff_cnt = 0;

  float sv[32];
#pragma unroll
  for (int i = 0; i < 32; ++i)
    sv[i] = s_base[(size_t)b * DIM + tid + i * 512];

  auto block_lse = [&]() -> double {
    float mloc = sv[0];
#pragma unroll
    for (int i = 1; i < 32; ++i) mloc = fmaxf(mloc, sv[i]);
    for (int o = 32; o; o >>= 1) mloc = fmaxf(mloc, __shfl_xor(mloc, o));
    if ((tid & 63) == 0) red_v[tid >> 6] = mloc;
    __syncthreads();
    const float m = fmaxf(fmaxf(fmaxf(red_v[0], red_v[1]), fmaxf(red_v[2], red_v[3])),
                          fmaxf(fmaxf(red_v[4], red_v[5]), fmaxf(red_v[6], red_v[7])));
    double ssum = 0.0;
#pragma unroll
    for (int i = 0; i < 32; ++i) ssum += exp((double)sv[i] - (double)m);
    for (int o = 32; o; o >>= 1) ssum += __shfl_xor(ssum, o);
    if ((tid & 63) == 0) red_d[tid >> 6] = ssum;
    __syncthreads();
    double tot = ((red_d[0] + red_d[1]) + (red_d[2] + red_d[3])) +
                 ((red_d[4] + red_d[5]) + (red_d[6] + red_d[7]));
    __syncthreads();
    return log(tot) + (double)m;
  };

  const double logZx = block_lse();

  int r = radius[b];
  if (r < 0) r = 0;
  if (r > 15) r = 15;
  const uint32_t jbase = (uint32_t)(b * DIM);

  for (int t = 0; t < r; ++t) {
    uint32_t kt0, kt1;
    tf2x32(0u, 42u, 0u, (uint32_t)t, kt0, kt1);   // fold_in(key(42), t)
    float bestv;
    int   besti;
    {
      uint32_t o0, o1;
      tf2x32(kt0, kt1, 0u, jbase + (uint32_t)tid, o0, o1);
      bestv = gt[(o0 ^ o1) >> 9] + sv[0];
      besti = tid;
    }
#pragma unroll
    for (int i = 1; i < 32; ++i) {
      const int d = tid + i * 512;
      uint32_t o0, o1;
      tf2x32(kt0, kt1, 0u, jbase + (uint32_t)d, o0, o1);  // partitionable ctr (0,j)
      const float val = gt[(o0 ^ o1) >> 9] + sv[i];
      if (val > bestv) { bestv = val; besti = d; }
    }
    for (int o = 32; o; o >>= 1) {
      const float ov = __shfl_xor(bestv, o);
      const int   oi = __shfl_xor(besti, o);
      if (ov > bestv || (ov == bestv && oi < besti)) { bestv = ov; besti = oi; }
    }
    if ((tid & 63) == 0) { red_v[tid >> 6] = bestv; red_i[tid >> 6] = besti; }
    __syncthreads();
    float bv = red_v[0]; int bi = red_i[0];
    for (int w = 1; w < 8; ++w)
      if (red_v[w] > bv || (red_v[w] == bv && red_i[w] < bi)) { bv = red_v[w]; bi = red_i[w]; }
    if ((bi & 511) == tid) {
      const int slot = bi >> 9;
#pragma unroll
      for (int i = 0; i < 32; ++i) if (i == slot) sv[i] = -sv[i];
    }
    if (tid == 0) {
      int found = -1;
      for (int j = 0; j < diff_cnt; ++j) if (diff[j] == bi) found = j;
      if (found >= 0) { diff[found] = diff[diff_cnt - 1]; diff_cnt -= 1; }
      else { diff[diff_cnt] = bi; diff_cnt += 1; }
    }
    __syncthreads();
  }

  const double lse_y = block_lse();

  const int dc_n = diff_cnt;
  for (int j = 0; j < dc_n; ++j) {
    const int d = diff[j];
    if ((d & 511) == tid) {
      const int slot = d >> 9;
#pragma unroll
      for (int i = 0; i < 32; ++i) if (i == slot) sflip[j] = sv[i];
    }
  }
  if (tid < dc_n) sgn_sh[tid] = 1.0f - 2.0f * x[(size_t)b * DIM + diff[tid]];
  __syncthreads();

  double dsp = 0.0;
  for (int rep = 0; rep < 2; ++rep) {
    const int hh = tid + rep * 512;
    const float hxv = h_base[(size_t)b * HID + hh];
    double delta = 0.0;
    for (int j = 0; j < dc_n; ++j)
      delta += (double)sgn_sh[j] * (double)W[(size_t)diff[j] * HID + hh];
    if (dc_n > 0) {
      const double hx = (double)hxv;
      dsp += softplus_d(hx + delta) - softplus_d(hx);
    }
  }
  for (int o = 32; o; o >>= 1) dsp += __shfl_xor(dsp, o);
  if ((tid & 63) == 0) red_d[tid >> 6] = dsp;
  __syncthreads();

  if (tid == 0) {
    const double dsp_tot = ((red_d[0] + red_d[1]) + (red_d[2] + red_d[3])) +
                           ((red_d[4] + red_d[5]) + (red_d[6] + red_d[7]));
    double dc = 0.0, ltilde = 0.0;
    for (int j = 0; j < dc_n; ++j) {
      dc += (double)sgn_sh[j] * (double)c[diff[j]];
      ltilde += 2.0 * (double)sflip[j];
    }
    double la = (dsp_tot + dc) + ltilde + (logZx - lse_y);
    if (la > 0.0) la = 0.0;
    const double p = exp(la);
    uint32_t ku0, ku1, o0, o1;
    tf2x32(0u, 42u, 0u, 16u, ku0, ku1);          // fold_in(key(42), 16)
    tf2x32(ku0, ku1, 0u, (uint32_t)b, o0, o1);   // ctr (0, b)
    const float ub = bits_to_unit_float(o0 ^ o1);
    accept_flag = (p >= (double)ub) ? 1 : 0;
  }
  __syncthreads();

  {
    const float4* xr = (const float4*)(x + (size_t)b * DIM);
    float4* orow = (float4*)(out + (size_t)b * DIM);
    for (int i = 0; i < DIM / 4 / 512; ++i)
      orow[i * 512 + tid] = xr[i * 512 + tid];
  }
  __syncthreads();
  if (accept_flag && tid < dc_n) {
    const int d = diff[tid];
    out[(size_t)b * DIM + d] = 1.0f - x[(size_t)b * DIM + d];
  }
}

// ------- K3w (R9 fast-path fallback): 1024-thread row scan -------
__global__ __launch_bounds__(1024) void row_kernel_w(
    const float* __restrict__ x, const float* __restrict__ W,
    const float* __restrict__ c, const int* __restrict__ radius,
    const float* __restrict__ h_base, const float* __restrict__ s_base,
    float* __restrict__ out) {
  const int b = blockIdx.x;
  const int tid = threadIdx.x;

  __shared__ float  red_v[16];
  __shared__ int    red_i[16];
  __shared__ double red_d[16];
  __shared__ int    diff[16];
  __shared__ float  sgn_sh[16];
  __shared__ float  sflip[16];
  __shared__ int    diff_cnt;
  __shared__ int    accept_flag;

  if (tid == 0) diff_cnt = 0;

  float sv[SV];
#pragma unroll
  for (int i = 0; i < SV; ++i)
    sv[i] = s_base[(size_t)b * DIM + tid + i * NT];

  auto tree16f = [&](const float* v) -> float {
    return fmaxf(fmaxf(fmaxf(fmaxf(v[0],v[1]),fmaxf(v[2],v[3])),
                       fmaxf(fmaxf(v[4],v[5]),fmaxf(v[6],v[7]))),
                 fmaxf(fmaxf(fmaxf(v[8],v[9]),fmaxf(v[10],v[11])),
                       fmaxf(fmaxf(v[12],v[13]),fmaxf(v[14],v[15]))));
  };
  auto tree16d = [&](const double* v) -> double {
    return ((((v[0]+v[1])+(v[2]+v[3])) + ((v[4]+v[5])+(v[6]+v[7])))
          + (((v[8]+v[9])+(v[10]+v[11])) + ((v[12]+v[13])+(v[14]+v[15]))));
  };

  auto block_lse = [&]() -> double {
    float mloc = sv[0];
#pragma unroll
    for (int i = 1; i < SV; ++i) mloc = fmaxf(mloc, sv[i]);
    for (int o = 32; o; o >>= 1) mloc = fmaxf(mloc, __shfl_xor(mloc, o));
    if ((tid & 63) == 0) red_v[tid >> 6] = mloc;
    __syncthreads();
    const float m = tree16f(red_v);
    double ssum = 0.0;
#pragma unroll
    for (int i = 0; i < SV; ++i) ssum += exp((double)sv[i] - (double)m);
    for (int o = 32; o; o >>= 1) ssum += __shfl_xor(ssum, o);
    if ((tid & 63) == 0) red_d[tid >> 6] = ssum;
    __syncthreads();
    double tot = tree16d(red_d);
    __syncthreads();
    return log(tot) + (double)m;
  };

  const double logZx = block_lse();

  int r = radius[b];
  if (r < 0) r = 0;
  if (r > 15) r = 15;
  const uint32_t jbase = (uint32_t)(b * DIM);

  for (int t = 0; t < r; ++t) {
    uint32_t kt0, kt1;
    tf2x32(0u, 42u, 0u, (uint32_t)t, kt0, kt1);
    float bestv;
    int   besti;
    {
      uint32_t o0, o1;
      tf2x32(kt0, kt1, 0u, jbase + (uint32_t)tid, o0, o1);
      bestv = bits_to_gumbel(o0 ^ o1) + sv[0];
      besti = tid;
    }
#pragma unroll
    for (int i = 1; i < SV; ++i) {
      const int d = tid + i * NT;
      uint32_t o0, o1;
      tf2x32(kt0, kt1, 0u, jbase + (uint32_t)d, o0, o1);
      const float val = bits_to_gumbel(o0 ^ o1) + sv[i];
      if (val > bestv) { bestv = val; besti = d; }
    }
    for (int o = 32; o; o >>= 1) {
      const float ov = __shfl_xor(bestv, o);
      const int   oi = __shfl_xor(besti, o);
      if (ov > bestv || (ov == bestv && oi < besti)) { bestv = ov; besti = oi; }
    }
    if ((tid & 63) == 0) { red_v[tid >> 6] = bestv; red_i[tid >> 6] = besti; }
    __syncthreads();
    float bv = red_v[0]; int bi = red_i[0];
    for (int w = 1; w < 16; ++w)
      if (red_v[w] > bv || (red_v[w] == bv && red_i[w] < bi)) { bv = red_v[w]; bi = red_i[w]; }
    if ((bi & (NT - 1)) == tid) {
      const int slot = bi >> 10;
#pragma unroll
      for (int i = 0; i < SV; ++i) if (i == slot) sv[i] = -sv[i];
    }
    if (tid == 0) {
      int found = -1;
      for (int j = 0; j < diff_cnt; ++j) if (diff[j] == bi) found = j;
      if (found >= 0) { diff[found] = diff[diff_cnt - 1]; diff_cnt -= 1; }
      else { diff[diff_cnt] = bi; diff_cnt += 1; }
    }
    __syncthreads();
  }

  const double lse_y = block_lse();

  const int dc_n = diff_cnt;
  for (int j = 0; j < dc_n; ++j) {
    const int d = diff[j];
    if ((d & (NT - 1)) == tid) {
      const int slot = d >> 10;
#pragma unroll
      for (int i = 0; i < SV; ++i) if (i == slot) sflip[j] = sv[i];
    }
  }
  if (tid < dc_n) sgn_sh[tid] = 1.0f - 2.0f * x[(size_t)b * DIM + diff[tid]];
  __syncthreads();

  double dsp = 0.0;
  {
    const int hh = tid;
    const float hxv = h_base[(size_t)b * HID + hh];
    double delta = 0.0;
    for (int j = 0; j < dc_n; ++j)
      delta += (double)sgn_sh[j] * (double)W[(size_t)diff[j] * HID + hh];
    if (dc_n > 0) {
      const double hx = (double)hxv;
      dsp += softplus_d(hx + delta) - softplus_d(hx);
    }
  }
  for (int o = 32; o; o >>= 1) dsp += __shfl_xor(dsp, o);
  if ((tid & 63) == 0) red_d[tid >> 6] = dsp;
  __syncthreads();

  if (tid == 0) {
    const double dsp_tot = tree16d(red_d);
    double dc = 0.0, ltilde = 0.0;
    for (int j = 0; j < dc_n; ++j) {
      dc += (double)sgn_sh[j] * (double)c[diff[j]];
      ltilde += 2.0 * (double)sflip[j];
    }
    double la = (dsp_tot + dc) + ltilde + (logZx - lse_y);
    if (la > 0.0) la = 0.0;
    const double p = exp(la);
    uint32_t ku0, ku1, o0, o1;
    tf2x32(0u, 42u, 0u, 16u, ku0, ku1);
    tf2x32(ku0, ku1, 0u, (uint32_t)b, o0, o1);
    const float ub = bits_to_unit_float(o0 ^ o1);
    accept_flag = (p >= (double)ub) ? 1 : 0;
  }
  __syncthreads();

  {
    const float4* xr = (const float4*)(x + (size_t)b * DIM);
    float4* orow = (float4*)(out + (size_t)b * DIM);
    for (int i = 0; i < DIM / 4 / NT; ++i)
      orow[i * NT + tid] = xr[i * NT + tid];
  }
  __syncthreads();
  if (accept_flag && tid < dc_n) {
    const int d = diff[tid];
    out[(size_t)b * DIM + d] = 1.0f - x[(size_t)b * DIM + d];
  }
}

// ------- K3 (two-phase fallback): BYTE-IDENTICAL to green R4/R7/R8 -------
__global__ __launch_bounds__(512) void row_kernel(
    const float* __restrict__ x, const float* __restrict__ W,
    const float* __restrict__ c, const int* __restrict__ radius,
    const float* __restrict__ h_base, const float* __restrict__ s_base,
    float* __restrict__ out, int b0) {
  const int lb = blockIdx.x;
  const int b  = b0 + lb;
  const int tid = threadIdx.x;

  __shared__ float  red_v[8];
  __shared__ int    red_i[8];
  __shared__ double red_d[8];
  __shared__ int    diff[16];
  __shared__ float  sgn_sh[16];
  __shared__ float  sflip[16];
  __shared__ int    diff_cnt;
  __shared__ int    accept_flag;

  if (tid == 0) diff_cnt = 0;

  float sv[32];
#pragma unroll
  for (int i = 0; i < 32; ++i)
    sv[i] = s_base[(size_t)lb * DIM + tid + i * 512];

  auto block_lse = [&]() -> double {
    float mloc = sv[0];
#pragma unroll
    for (int i = 1; i < 32; ++i) mloc = fmaxf(mloc, sv[i]);
    for (int o = 32; o; o >>= 1) mloc = fmaxf(mloc, __shfl_xor(mloc, o));
    if ((tid & 63) == 0) red_v[tid >> 6] = mloc;
    __syncthreads();
    const float m = fmaxf(fmaxf(fmaxf(red_v[0], red_v[1]), fmaxf(red_v[2], red_v[3])),
                          fmaxf(fmaxf(red_v[4], red_v[5]), fmaxf(red_v[6], red_v[7])));
    double ssum = 0.0;
#pragma unroll
    for (int i = 0; i < 32; ++i) ssum += exp((double)sv[i] - (double)m);
    for (int o = 32; o; o >>= 1) ssum += __shfl_xor(ssum, o);
    if ((tid & 63) == 0) red_d[tid >> 6] = ssum;
    __syncthreads();
    double tot = ((red_d[0] + red_d[1]) + (red_d[2] + red_d[3])) +
                 ((red_d[4] + red_d[5]) + (red_d[6] + red_d[7]));
    __syncthreads();
    return log(tot) + (double)m;
  };

  const double logZx = block_lse();

  int r = radius[b];
  if (r < 0) r = 0;
  if (r > 15) r = 15;
  const uint32_t jbase = (uint32_t)(b * DIM);

  for (int t = 0; t < r; ++t) {
    uint32_t kt0, kt1;
    tf2x32(0u, 42u, 0u, (uint32_t)t, kt0, kt1);
    float bestv;
    int   besti;
    {
      uint32_t o0, o1;
      tf2x32(kt0, kt1, 0u, jbase + (uint32_t)tid, o0, o1);
      bestv = bits_to_gumbel(o0 ^ o1) + sv[0];
      besti = tid;
    }
#pragma unroll
    for (int i = 1; i < 32; ++i) {
      const int d = tid + i * 512;
      uint32_t o0, o1;
      tf2x32(kt0, kt1, 0u, jbase + (uint32_t)d, o0, o1);
      const float val = bits_to_gumbel(o0 ^ o1) + sv[i];
      if (val > bestv) { bestv = val; besti = d; }
    }
    for (int o = 32; o; o >>= 1) {
      const float ov = __shfl_xor(bestv, o);
      const int   oi = __shfl_xor(besti, o);
      if (ov > bestv || (ov == bestv && oi < besti)) { bestv = ov; besti = oi; }
    }
    if ((tid & 63) == 0) { red_v[tid >> 6] = bestv; red_i[tid >> 6] = besti; }
    __syncthreads();
    float bv = red_v[0]; int bi = red_i[0];
    for (int w = 1; w < 8; ++w)
      if (red_v[w] > bv || (red_v[w] == bv && red_i[w] < bi)) { bv = red_v[w]; bi = red_i[w]; }
    if ((bi & 511) == tid) {
      const int slot = bi >> 9;
#pragma unroll
      for (int i = 0; i < 32; ++i) if (i == slot) sv[i] = -sv[i];
    }
    if (tid == 0) {
      int found = -1;
      for (int j = 0; j < diff_cnt; ++j) if (diff[j] == bi) found = j;
      if (found >= 0) { diff[found] = diff[diff_cnt - 1]; diff_cnt -= 1; }
      else { diff[diff_cnt] = bi; diff_cnt += 1; }
    }
    __syncthreads();
  }

  const double lse_y = block_lse();

  const int dc_n = diff_cnt;
  for (int j = 0; j < dc_n; ++j) {
    const int d = diff[j];
    if ((d & 511) == tid) {
      const int slot = d >> 9;
#pragma unroll
      for (int i = 0; i < 32; ++i) if (i == slot) sflip[j] = sv[i];
    }
  }
  if (tid < dc_n) sgn_sh[tid] = 1.0f - 2.0f * x[(size_t)b * DIM + diff[tid]];
  __syncthreads();

  double dsp = 0.0;
  for (int rep = 0; rep < 2; ++rep) {
    const int hh = tid + rep * 512;
    const float hxv = h_base[(size_t)lb * HID + hh];
    double delta = 0.0;
    for (int j = 0; j < dc_n; ++j)
      delta += (double)sgn_sh[j] * (double)W[(size_t)diff[j] * HID + hh];
    if (dc_n > 0) {
      const double hx = (double)hxv;
      dsp += softplus_d(hx + delta) - softplus_d(hx);
    }
  }
  for (int o = 32; o; o >>= 1) dsp += __shfl_xor(dsp, o);
  if ((tid & 63) == 0) red_d[tid >> 6] = dsp;
  __syncthreads();

  if (tid == 0) {
    const double dsp_tot = ((red_d[0] + red_d[1]) + (red_d[2] + red_d[3])) +
                           ((red_d[4] + red_d[5]) + (red_d[6] + red_d[7]));
    double dc = 0.0, ltilde = 0.0;
    for (int j = 0; j < dc_n; ++j) {
      dc += (double)sgn_sh[j] * (double)c[diff[j]];
      ltilde += 2.0 * (double)sflip[j];
    }
    double la = (dsp_tot + dc) + ltilde + (logZx - lse_y);
    if (la > 0.0) la = 0.0;
    const double p = exp(la);
    uint32_t ku0, ku1, o0, o1;
    tf2x32(0u, 42u, 0u, 16u, ku0, ku1);
    tf2x32(ku0, ku1, 0u, (uint32_t)b, o0, o1);
    const float ub = bits_to_unit_float(o0 ^ o1);
    accept_flag = (p >= (double)ub) ? 1 : 0;
  }
  __syncthreads();

  {
    const float4* xr = (const float4*)(x + (size_t)b * DIM);
    float4* orow = (float4*)(out + (size_t)b * DIM);
    for (int i = 0; i < DIM / 4 / 512; ++i)
      orow[i * 512 + tid] = xr[i * 512 + tid];
  }
  __syncthreads();
  if (accept_flag && tid < dc_n) {
    const int d = diff[tid];
    out[(size_t)b * DIM + d] = 1.0f - x[(size_t)b * DIM + d];
  }
}

// ---------------- launch ----------------
extern "C" void kernel_launch(void* const* d_in, const int* in_sizes, int n_in,
                              void* d_out, int out_size, void* d_ws, size_t ws_size,
                              hipStream_t stream) {
  const float* x      = (const float*)d_in[0];
  const float* W      = (const float*)d_in[1];
  const float* bh     = (const float*)d_in[2];
  const float* c      = (const float*)d_in[3];
  const int*   radius = (const int*)d_in[4];
  float* out = (float*)d_out;
  const size_t F = sizeof(float);

  if (ws_size >= ((size_t)2 * BSIZE * HID + GTN) * F) {
    // ---------- TABLE single-phase: ws = [h 4MB][sig 4MB][gtable 32MB] ----------
    float* h_ws   = (float*)d_ws;
    float* sig_ws = h_ws + (size_t)BSIZE * HID;
    float* gtable = sig_ws + (size_t)BSIZE * HID;
    float* P      = out;

    fill_gtable_kernel<<<GTN / 256, 256, 0, stream>>>(gtable);

    dim3 g1(HID / 128, BSIZE / 128, SPLITK);
    gemm_h_split_kernel<<<g1, 256, 0, stream>>>(x, W, P);

    reduce_h_sig_kernel<<<(BSIZE * HID / 4) / 256, 256, 0, stream>>>(P, bh, h_ws, sig_ws);

    dim3 g2(BSIZE / 128, DIM / 128);
    gemm2_sig128_kernel<<<g2, 256, 0, stream>>>(sig_ws, W, c, x, out);

    row_kernel_t<<<BSIZE, 512, 0, stream>>>(x, W, c, radius, h_ws, out, gtable, out);
  } else if (ws_size >= (size_t)2 * BSIZE * HID * F) {
    // ---------- R9 fast single-phase (no table) ----------
    float* h_ws   = (float*)d_ws;
    float* sig_ws = h_ws + (size_t)BSIZE * HID;
    float* P      = out;

    dim3 g1(HID / 128, BSIZE / 128, SPLITK);
    gemm_h_split_kernel<<<g1, 256, 0, stream>>>(x, W, P);
    reduce_h_sig_kernel<<<(BSIZE * HID / 4) / 256, 256, 0, stream>>>(P, bh, h_ws, sig_ws);
    dim3 g2(BSIZE / 128, DIM / 128);
    gemm2_sig128_kernel<<<g2, 256, 0, stream>>>(sig_ws, W, c, x, out);
    row_kernel_w<<<BSIZE, NT, 0, stream>>>(x, W, c, radius, h_ws, out, out);
  } else if (ws_size >= (size_t)(64 + BSIZE) * HID * F) {
    // ---------- R8 two-phase with sig ----------
    float* stash = (float*)d_ws;
    float* sig   = (float*)d_ws + (size_t)64 * HID;
    float* h_tail = out + TAIL;
    float* P      = out;

    dim3 g1(HID / 128, BSIZE / 128, SPLITK);
    gemm_h_split_kernel<<<g1, 256, 0, stream>>>(x, W, P);
    reduce_h_sig_kernel<<<(BSIZE * HID / 4) / 256, 256, 0, stream>>>(P, bh, h_tail, sig);
    copy_stash_kernel<<<64, 256, 0, stream>>>(h_tail + (size_t)960 * HID, stash);

    dim3 g2a(960 / 64, DIM / 128);
    gemm2_sig_kernel<<<g2a, 256, 0, stream>>>(sig, W, c, x, out, 0);
    row_kernel<<<960, 512, 0, stream>>>(x, W, c, radius, h_tail, out, out, 0);

    dim3 g2b(1, DIM / 128);
    gemm2_sig_kernel<<<g2b, 256, 0, stream>>>(sig + (size_t)960 * HID, W, c, x, out + TAIL, 960);
    row_kernel<<<64, 512, 0, stream>>>(x, W, c, radius, stash, out + TAIL, out, 960);
  } else if (ws_size >= (size_t)64 * HID * F) {
    // ---------- R8 two-phase without sig ----------
    float* stash = (float*)d_ws;
    float* h_tail = out + TAIL;
    float* P      = out;

    dim3 g1(HID / 128, BSIZE / 128, SPLITK);
    gemm_h_split_kernel<<<g1, 256, 0, stream>>>(x, W, P);
    reduce_h_sig_kernel<<<(BSIZE * HID / 4) / 256, 256, 0, stream>>>(P, bh, h_tail, nullptr);
    copy_stash_kernel<<<64, 256, 0, stream>>>(h_tail + (size_t)960 * HID, stash);

    dim3 g2a(960 / 64, DIM / 128);
    gemm2_kernel<<<g2a, 256, 0, stream>>>(h_tail, W, c, x, out, 0);
    row_kernel<<<960, 512, 0, stream>>>(x, W, c, radius, h_tail, out, out, 0);

    dim3 g2b(1, DIM / 128);
    gemm2_kernel<<<g2b, 256, 0, stream>>>(stash, W, c, x, out + TAIL, 960);
    row_kernel<<<64, 512, 0, stream>>>(x, W, c, radius, stash, out + TAIL, out, 960);
  }
}

// Round 11
// 1733.450 us; speedup vs baseline: 1.8069x; 1.8069x over previous
//
#include <hip/hip_runtime.h>
#include <stdint.h>

#define BSIZE 1024
#define DIM   16384
#define HID   1024
#define SPLITK 8
#define KC     (DIM / SPLITK)       /* 2048 */
#define NT    1024                  /* R9-fallback wide row kernel */
#define SV    (DIM / NT)
#define NBKT  1024                  /* gumbel bound buckets (top 10 mantissa bits) */

// ---------------- threefry2x32 (JAX-compatible, 20 rounds) ----------------
__device__ __forceinline__ void tf2x32(uint32_t k0, uint32_t k1,
                                       uint32_t x0, uint32_t x1,
                                       uint32_t& o0, uint32_t& o1) {
  const uint32_t ks2 = k0 ^ k1 ^ 0x1BD11BDAu;
#define TFR(r) { x0 += x1; x1 = (x1 << r) | (x1 >> (32 - r)); x1 ^= x0; }
  x0 += k0; x1 += k1;
  TFR(13) TFR(15) TFR(26) TFR(6)
  x0 += k1;  x1 += ks2 + 1u;
  TFR(17) TFR(29) TFR(16) TFR(24)
  x0 += ks2; x1 += k0 + 2u;
  TFR(13) TFR(15) TFR(26) TFR(6)
  x0 += k0;  x1 += k1 + 3u;
  TFR(17) TFR(29) TFR(16) TFR(24)
  x0 += k1;  x1 += ks2 + 4u;
  TFR(13) TFR(15) TFR(26) TFR(6)
  x0 += ks2; x1 += k0 + 5u;
#undef TFR
  o0 = x0; o1 = x1;
}

__device__ __forceinline__ float bits_to_unit_float(uint32_t bits) {
  return __uint_as_float((bits >> 9) | 0x3f800000u) - 1.0f;
}

__device__ __forceinline__ float bits_to_gumbel(uint32_t bits) {
  float u = bits_to_unit_float(bits);
  if (u == 0.0f) u = 1.1754943508222875e-38f;   // minval = finfo(f32).tiny
  float l1 = (float)log((double)u);
  float nl1 = -l1;
  float l2 = (float)log((double)nl1);
  return -l2;
}

__device__ __forceinline__ double softplus_d(double z) {
  return (z > 0.0) ? (z + log1p(exp(-z))) : log1p(exp(z));
}

// ------- K0: per-bucket EXACT gumbel bounds (monotone in mantissa) -------
__global__ __launch_bounds__(256) void fill_gbounds_kernel(
    float* __restrict__ gminb, float* __restrict__ gmaxb) {
  const uint32_t i = blockIdx.x * 256 + threadIdx.x;   // [0, 1024)
  const uint32_t mlo = i << 13;
  const uint32_t mhi = mlo + 8191u;
  gminb[i] = bits_to_gumbel(mlo << 9);
  gmaxb[i] = bits_to_gumbel(mhi << 9);
}

// ------- K1: split-K GEMM  P[s] = x[:, sKC:(s+1)KC] @ W[sKC:...]  (128x128) -------
__global__ __launch_bounds__(256) void gemm_h_split_kernel(
    const float* __restrict__ x, const float* __restrict__ W,
    float* __restrict__ P) {
  __shared__ float Al[32][128];
  __shared__ float Bl[32][128];
  const int tid = threadIdx.x;
  const int n0 = blockIdx.x * 128;
  const int m0 = blockIdx.y * 128;
  const int s  = blockIdx.z;
  const int arow = tid >> 1, akof = (tid & 1) * 16;
  const int brow = tid >> 3, bcol = (tid & 7) * 16;
  const int ty = tid >> 4, tx = tid & 15;

  float acc[8][8];
  for (int i = 0; i < 8; ++i)
    for (int j = 0; j < 8; ++j) acc[i][j] = 0.0f;

  for (int kt = 0; kt < KC / 32; ++kt) {
    const int k0 = s * KC + kt * 32;
    const float* ap = x + (size_t)(m0 + arow) * DIM + k0 + akof;
    float4 av0 = *(const float4*)(ap + 0);
    float4 av1 = *(const float4*)(ap + 4);
    float4 av2 = *(const float4*)(ap + 8);
    float4 av3 = *(const float4*)(ap + 12);
    const float* bp = W + (size_t)(k0 + brow) * HID + n0 + bcol;
    float4 bv0 = *(const float4*)(bp + 0);
    float4 bv1 = *(const float4*)(bp + 4);
    float4 bv2 = *(const float4*)(bp + 8);
    float4 bv3 = *(const float4*)(bp + 12);
    __syncthreads();
    {
      float ta[16] = {av0.x,av0.y,av0.z,av0.w, av1.x,av1.y,av1.z,av1.w,
                      av2.x,av2.y,av2.z,av2.w, av3.x,av3.y,av3.z,av3.w};
      for (int e = 0; e < 16; ++e) Al[akof + e][arow] = ta[e];
    }
    *(float4*)&Bl[brow][bcol + 0]  = bv0;
    *(float4*)&Bl[brow][bcol + 4]  = bv1;
    *(float4*)&Bl[brow][bcol + 8]  = bv2;
    *(float4*)&Bl[brow][bcol + 12] = bv3;
    __syncthreads();
#pragma unroll 4
    for (int k = 0; k < 32; ++k) {
      const float4 a0 = *(const float4*)&Al[k][ty * 8];
      const float4 a1 = *(const float4*)&Al[k][ty * 8 + 4];
      const float4 b0 = *(const float4*)&Bl[k][tx * 8];
      const float4 b1 = *(const float4*)&Bl[k][tx * 8 + 4];
      const float a[8]  = {a0.x,a0.y,a0.z,a0.w, a1.x,a1.y,a1.z,a1.w};
      const float bb[8] = {b0.x,b0.y,b0.z,b0.w, b1.x,b1.y,b1.z,b1.w};
      for (int i = 0; i < 8; ++i)
        for (int j = 0; j < 8; ++j)
          acc[i][j] = fmaf(a[i], bb[j], acc[i][j]);
    }
  }
  float* Cp = P + (size_t)s * (BSIZE * HID);
  for (int i = 0; i < 8; ++i) {
    const int gm = m0 + ty * 8 + i;
    float4 w0 = {acc[i][0], acc[i][1], acc[i][2], acc[i][3]};
    float4 w1 = {acc[i][4], acc[i][5], acc[i][6], acc[i][7]};
    *(float4*)(Cp + (size_t)gm * HID + n0 + tx * 8 + 0) = w0;
    *(float4*)(Cp + (size_t)gm * HID + n0 + tx * 8 + 4) = w1;
  }
}

// ------- K1r: h = sum_s P[s] + bh (fixed order) -> hbuf; sig (f64-exact) -------
__global__ __launch_bounds__(256) void reduce_h_sig_kernel(
    const float* __restrict__ P, const float* __restrict__ bh,
    float* __restrict__ hbuf, float* __restrict__ sig) {
  const int i = blockIdx.x * 256 + threadIdx.x;   // float4 idx, 262144 total
  float4 a = ((const float4*)P)[i];
  for (int s = 1; s < SPLITK; ++s) {
    float4 p = ((const float4*)P)[(size_t)s * (BSIZE * HID / 4) + i];
    a.x += p.x; a.y += p.y; a.z += p.z; a.w += p.w;
  }
  float4 bv = ((const float4*)bh)[i & (HID / 4 - 1)];
  float4 h;
  h.x = a.x + bv.x; h.y = a.y + bv.y; h.z = a.z + bv.z; h.w = a.w + bv.w;
  ((float4*)hbuf)[i] = h;
  float4 sg;
  sg.x = (float)(1.0 / (1.0 + exp(-(double)h.x)));
  sg.y = (float)(1.0 / (1.0 + exp(-(double)h.y)));
  sg.z = (float)(1.0 / (1.0 + exp(-(double)h.z)));
  sg.w = (float)(1.0 / (1.0 + exp(-(double)h.w)));
  ((float4*)sig)[i] = sg;
}

// -- K2s128: s = (1-2x)*(sig @ W^T + c)*0.5, 128x128 tiles --
__global__ __launch_bounds__(256) void gemm2_sig128_kernel(
    const float* __restrict__ sig_src, const float* __restrict__ W,
    const float* __restrict__ c, const float* __restrict__ x,
    float* __restrict__ s_dst) {
  __shared__ float Al[32][128];
  __shared__ float Bl[32][128];
  const int tid = threadIdx.x;
  const int m0 = blockIdx.x * 128;
  const int n0 = blockIdx.y * 128;
  const int row2 = tid >> 1, kof = (tid & 1) * 16;
  const int ty = tid >> 4, tx = tid & 15;

  float acc[8][8];
  for (int i = 0; i < 8; ++i)
    for (int j = 0; j < 8; ++j) acc[i][j] = 0.0f;

  for (int kt = 0; kt < HID / 32; ++kt) {
    const int k0 = kt * 32;
    const float* ap = sig_src + (size_t)(m0 + row2) * HID + k0 + kof;
    float4 av0 = *(const float4*)(ap + 0);
    float4 av1 = *(const float4*)(ap + 4);
    float4 av2 = *(const float4*)(ap + 8);
    float4 av3 = *(const float4*)(ap + 12);
    const float* bp = W + (size_t)(n0 + row2) * HID + k0 + kof;
    float4 bv0 = *(const float4*)(bp + 0);
    float4 bv1 = *(const float4*)(bp + 4);
    float4 bv2 = *(const float4*)(bp + 8);
    float4 bv3 = *(const float4*)(bp + 12);
    __syncthreads();
    {
      float ta[16] = {av0.x,av0.y,av0.z,av0.w, av1.x,av1.y,av1.z,av1.w,
                      av2.x,av2.y,av2.z,av2.w, av3.x,av3.y,av3.z,av3.w};
      float tb[16] = {bv0.x,bv0.y,bv0.z,bv0.w, bv1.x,bv1.y,bv1.z,bv1.w,
                      bv2.x,bv2.y,bv2.z,bv2.w, bv3.x,bv3.y,bv3.z,bv3.w};
      for (int e = 0; e < 16; ++e) { Al[kof + e][row2] = ta[e]; Bl[kof + e][row2] = tb[e]; }
    }
    __syncthreads();
#pragma unroll 4
    for (int k = 0; k < 32; ++k) {
      const float4 a0 = *(const float4*)&Al[k][ty * 8];
      const float4 a1 = *(const float4*)&Al[k][ty * 8 + 4];
      const float4 b0 = *(const float4*)&Bl[k][tx * 8];
      const float4 b1 = *(const float4*)&Bl[k][tx * 8 + 4];
      const float a[8]  = {a0.x,a0.y,a0.z,a0.w, a1.x,a1.y,a1.z,a1.w};
      const float bb[8] = {b0.x,b0.y,b0.z,b0.w, b1.x,b1.y,b1.z,b1.w};
      for (int i = 0; i < 8; ++i)
        for (int j = 0; j < 8; ++j)
          acc[i][j] = fmaf(a[i], bb[j], acc[i][j]);
    }
  }
  for (int i = 0; i < 8; ++i) {
    const int gm = m0 + ty * 8 + i;
    const size_t rowoff = (size_t)gm * DIM + n0 + tx * 8;
    for (int q = 0; q < 2; ++q) {
      float4 xv = *(const float4*)(x + rowoff + q * 4);
      float4 cv = *(const float4*)(c + n0 + tx * 8 + q * 4);
      float g0 = acc[i][q * 4 + 0] + cv.x;
      float g1 = acc[i][q * 4 + 1] + cv.y;
      float g2 = acc[i][q * 4 + 2] + cv.z;
      float g3 = acc[i][q * 4 + 3] + cv.w;
      float4 sv;
      sv.x = ((xv.x == 1.0f) ? -g0 : g0) * 0.5f;
      sv.y = ((xv.y == 1.0f) ? -g1 : g1) * 0.5f;
      sv.z = ((xv.z == 1.0f) ? -g2 : g2) * 0.5f;
      sv.w = ((xv.w == 1.0f) ? -g3 : g3) * 0.5f;
      *(float4*)(s_dst + rowoff + q * 4) = sv;
    }
  }
}

// ------- K3f: green 512-thread row kernel + exact interval-bound filter.
// Pass 1: L = max(gmin[bkt]+s) (exact lower bound, no transcendentals).
// Pass 2: exact f64 gumbel ONLY where gmax[bkt]+s >= L (provable superset
// of the winner and all ties -> bit-identical selection). -------
__global__ __launch_bounds__(512) void row_kernel_f(
    const float* __restrict__ x, const float* __restrict__ W,
    const float* __restrict__ c, const int* __restrict__ radius,
    const float* __restrict__ h_base,   // + b*HID
    const float* __restrict__ s_base,   // + b*DIM
    const float* __restrict__ gminb, const float* __restrict__ gmaxb,
    float* __restrict__ out) {
  const int b = blockIdx.x;
  const int tid = threadIdx.x;

  __shared__ float  gmin_l[NBKT];
  __shared__ float  gmax_l[NBKT];
  __shared__ float  red_v[8];
  __shared__ int    red_i[8];
  __shared__ double red_d[8];
  __shared__ int    diff[16];
  __shared__ float  sgn_sh[16];
  __shared__ float  sflip[16];
  __shared__ int    diff_cnt;
  __shared__ int    accept_flag;

  if (tid == 0) diff_cnt = 0;
  gmin_l[tid]       = gminb[tid];
  gmin_l[tid + 512] = gminb[tid + 512];
  gmax_l[tid]       = gmaxb[tid];
  gmax_l[tid + 512] = gmaxb[tid + 512];

  float sv[32];
#pragma unroll
  for (int i = 0; i < 32; ++i)
    sv[i] = s_base[(size_t)b * DIM + tid + i * 512];
  __syncthreads();   // tables visible

  auto block_lse = [&]() -> double {
    float mloc = sv[0];
#pragma unroll
    for (int i = 1; i < 32; ++i) mloc = fmaxf(mloc, sv[i]);
    for (int o = 32; o; o >>= 1) mloc = fmaxf(mloc, __shfl_xor(mloc, o));
    if ((tid & 63) == 0) red_v[tid >> 6] = mloc;
    __syncthreads();
    const float m = fmaxf(fmaxf(fmaxf(red_v[0], red_v[1]), fmaxf(red_v[2], red_v[3])),
                          fmaxf(fmaxf(red_v[4], red_v[5]), fmaxf(red_v[6], red_v[7])));
    double ssum = 0.0;
#pragma unroll
    for (int i = 0; i < 32; ++i) ssum += exp((double)sv[i] - (double)m);
    for (int o = 32; o; o >>= 1) ssum += __shfl_xor(ssum, o);
    if ((tid & 63) == 0) red_d[tid >> 6] = ssum;
    __syncthreads();
    double tot = ((red_d[0] + red_d[1]) + (red_d[2] + red_d[3])) +
                 ((red_d[4] + red_d[5]) + (red_d[6] + red_d[7]));
    __syncthreads();
    return log(tot) + (double)m;
  };

  const double logZx = block_lse();

  int r = radius[b];
  if (r < 0) r = 0;
  if (r > 15) r = 15;
  const uint32_t jbase = (uint32_t)(b * DIM);

  for (int t = 0; t < r; ++t) {
    uint32_t kt0, kt1;
    tf2x32(0u, 42u, 0u, (uint32_t)t, kt0, kt1);   // fold_in(key(42), t)

    // ---- pass 1: exact lower bound L of the row max ----
    float lbmax = -3.402823466e38f;
#pragma unroll
    for (int i = 0; i < 32; ++i) {
      const int d = tid + (i << 9);
      uint32_t o0, o1;
      tf2x32(kt0, kt1, 0u, jbase + (uint32_t)d, o0, o1);
      const uint32_t bits = o0 ^ o1;
      lbmax = fmaxf(lbmax, gmin_l[bits >> 22] + sv[i]);
    }
    for (int o = 32; o; o >>= 1) lbmax = fmaxf(lbmax, __shfl_xor(lbmax, o));
    if ((tid & 63) == 0) red_v[tid >> 6] = lbmax;
    __syncthreads();
    const float L = fmaxf(fmaxf(fmaxf(red_v[0], red_v[1]), fmaxf(red_v[2], red_v[3])),
                          fmaxf(fmaxf(red_v[4], red_v[5]), fmaxf(red_v[6], red_v[7])));
    __syncthreads();   // red_v free for winner reduce

    // ---- pass 2: exact eval only where upper bound can reach L ----
    float bestv = -3.402823466e38f;
    int   besti = 0x7fffffff;
#pragma unroll
    for (int i = 0; i < 32; ++i) {
      const int d = tid + (i << 9);
      uint32_t o0, o1;
      tf2x32(kt0, kt1, 0u, jbase + (uint32_t)d, o0, o1);
      const uint32_t bits = o0 ^ o1;
      if (gmax_l[bits >> 22] + sv[i] >= L) {
        const float val = bits_to_gumbel(bits) + sv[i];   // exact path
        if (val > bestv) { bestv = val; besti = d; }
      }
    }
    for (int o = 32; o; o >>= 1) {
      const float ov = __shfl_xor(bestv, o);
      const int   oi = __shfl_xor(besti, o);
      if (ov > bestv || (ov == bestv && oi < besti)) { bestv = ov; besti = oi; }
    }
    if ((tid & 63) == 0) { red_v[tid >> 6] = bestv; red_i[tid >> 6] = besti; }
    __syncthreads();
    float bv = red_v[0]; int bi = red_i[0];
    for (int w = 1; w < 8; ++w)
      if (red_v[w] > bv || (red_v[w] == bv && red_i[w] < bi)) { bv = red_v[w]; bi = red_i[w]; }
    if ((bi & 511) == tid) {
      const int slot = bi >> 9;
#pragma unroll
      for (int i = 0; i < 32; ++i) if (i == slot) sv[i] = -sv[i];
    }
    if (tid == 0) {
      int found = -1;
      for (int j = 0; j < diff_cnt; ++j) if (diff[j] == bi) found = j;
      if (found >= 0) { diff[found] = diff[diff_cnt - 1]; diff_cnt -= 1; }
      else { diff[diff_cnt] = bi; diff_cnt += 1; }
    }
    __syncthreads();
  }

  const double lse_y = block_lse();

  const int dc_n = diff_cnt;
  for (int j = 0; j < dc_n; ++j) {
    const int d = diff[j];
    if ((d & 511) == tid) {
      const int slot = d >> 9;
#pragma unroll
      for (int i = 0; i < 32; ++i) if (i == slot) sflip[j] = sv[i];
    }
  }
  if (tid < dc_n) sgn_sh[tid] = 1.0f - 2.0f * x[(size_t)b * DIM + diff[tid]];
  __syncthreads();

  double dsp = 0.0;
  for (int rep = 0; rep < 2; ++rep) {
    const int hh = tid + rep * 512;
    const float hxv = h_base[(size_t)b * HID + hh];
    double delta = 0.0;
    for (int j = 0; j < dc_n; ++j)
      delta += (double)sgn_sh[j] * (double)W[(size_t)diff[j] * HID + hh];
    if (dc_n > 0) {
      const double hx = (double)hxv;
      dsp += softplus_d(hx + delta) - softplus_d(hx);
    }
  }
  for (int o = 32; o; o >>= 1) dsp += __shfl_xor(dsp, o);
  if ((tid & 63) == 0) red_d[tid >> 6] = dsp;
  __syncthreads();

  if (tid == 0) {
    const double dsp_tot = ((red_d[0] + red_d[1]) + (red_d[2] + red_d[3])) +
                           ((red_d[4] + red_d[5]) + (red_d[6] + red_d[7]));
    double dc = 0.0, ltilde = 0.0;
    for (int j = 0; j < dc_n; ++j) {
      dc += (double)sgn_sh[j] * (double)c[diff[j]];
      ltilde += 2.0 * (double)sflip[j];
    }
    double la = (dsp_tot + dc) + ltilde + (logZx - lse_y);
    if (la > 0.0) la = 0.0;
    const double p = exp(la);
    uint32_t ku0, ku1, o0, o1;
    tf2x32(0u, 42u, 0u, 16u, ku0, ku1);          // fold_in(key(42), 16)
    tf2x32(ku0, ku1, 0u, (uint32_t)b, o0, o1);   // ctr (0, b)
    const float ub = bits_to_unit_float(o0 ^ o1);
    accept_flag = (p >= (double)ub) ? 1 : 0;
  }
  __syncthreads();

  {
    const float4* xr = (const float4*)(x + (size_t)b * DIM);
    float4* orow = (float4*)(out + (size_t)b * DIM);
    for (int i = 0; i < DIM / 4 / 512; ++i)
      orow[i * 512 + tid] = xr[i * 512 + tid];
  }
  __syncthreads();
  if (accept_flag && tid < dc_n) {
    const int d = diff[tid];
    out[(size_t)b * DIM + d] = 1.0f - x[(size_t)b * DIM + d];
  }
}

// ------- K3w (R9 fallback): 1024-thread exact row scan (proven 2348 total) -------
__global__ __launch_bounds__(1024) void row_kernel_w(
    const float* __restrict__ x, const float* __restrict__ W,
    const float* __restrict__ c, const int* __restrict__ radius,
    const float* __restrict__ h_base, const float* __restrict__ s_base,
    float* __restrict__ out) {
  const int b = blockIdx.x;
  const int tid = threadIdx.x;

  __shared__ float  red_v[16];
  __shared__ int    red_i[16];
  __shared__ double red_d[16];
  __shared__ int    diff[16];
  __shared__ float  sgn_sh[16];
  __shared__ float  sflip[16];
  __shared__ int    diff_cnt;
  __shared__ int    accept_flag;

  if (tid == 0) diff_cnt = 0;

  float sv[SV];
#pragma unroll
  for (int i = 0; i < SV; ++i)
    sv[i] = s_base[(size_t)b * DIM + tid + i * NT];

  auto tree16f = [&](const float* v) -> float {
    return fmaxf(fmaxf(fmaxf(fmaxf(v[0],v[1]),fmaxf(v[2],v[3])),
                       fmaxf(fmaxf(v[4],v[5]),fmaxf(v[6],v[7]))),
                 fmaxf(fmaxf(fmaxf(v[8],v[9]),fmaxf(v[10],v[11])),
                       fmaxf(fmaxf(v[12],v[13]),fmaxf(v[14],v[15]))));
  };
  auto tree16d = [&](const double* v) -> double {
    return ((((v[0]+v[1])+(v[2]+v[3])) + ((v[4]+v[5])+(v[6]+v[7])))
          + (((v[8]+v[9])+(v[10]+v[11])) + ((v[12]+v[13])+(v[14]+v[15]))));
  };

  auto block_lse = [&]() -> double {
    float mloc = sv[0];
#pragma unroll
    for (int i = 1; i < SV; ++i) mloc = fmaxf(mloc, sv[i]);
    for (int o = 32; o; o >>= 1) mloc = fmaxf(mloc, __shfl_xor(mloc, o));
    if ((tid & 63) == 0) red_v[tid >> 6] = mloc;
    __syncthreads();
    const float m = tree16f(red_v);
    double ssum = 0.0;
#pragma unroll
    for (int i = 0; i < SV; ++i) ssum += exp((double)sv[i] - (double)m);
    for (int o = 32; o; o >>= 1) ssum += __shfl_xor(ssum, o);
    if ((tid & 63) == 0) red_d[tid >> 6] = ssum;
    __syncthreads();
    double tot = tree16d(red_d);
    __syncthreads();
    return log(tot) + (double)m;
  };

  const double logZx = block_lse();

  int r = radius[b];
  if (r < 0) r = 0;
  if (r > 15) r = 15;
  const uint32_t jbase = (uint32_t)(b * DIM);

  for (int t = 0; t < r; ++t) {
    uint32_t kt0, kt1;
    tf2x32(0u, 42u, 0u, (uint32_t)t, kt0, kt1);
    float bestv;
    int   besti;
    {
      uint32_t o0, o1;
      tf2x32(kt0, kt1, 0u, jbase + (uint32_t)tid, o0, o1);
      bestv = bits_to_gumbel(o0 ^ o1) + sv[0];
      besti = tid;
    }
#pragma unroll
    for (int i = 1; i < SV; ++i) {
      const int d = tid + i * NT;
      uint32_t o0, o1;
      tf2x32(kt0, kt1, 0u, jbase + (uint32_t)d, o0, o1);
      const float val = bits_to_gumbel(o0 ^ o1) + sv[i];
      if (val > bestv) { bestv = val; besti = d; }
    }
    for (int o = 32; o; o >>= 1) {
      const float ov = __shfl_xor(bestv, o);
      const int   oi = __shfl_xor(besti, o);
      if (ov > bestv || (ov == bestv && oi < besti)) { bestv = ov; besti = oi; }
    }
    if ((tid & 63) == 0) { red_v[tid >> 6] = bestv; red_i[tid >> 6] = besti; }
    __syncthreads();
    float bv = red_v[0]; int bi = red_i[0];
    for (int w = 1; w < 16; ++w)
      if (red_v[w] > bv || (red_v[w] == bv && red_i[w] < bi)) { bv = red_v[w]; bi = red_i[w]; }
    if ((bi & (NT - 1)) == tid) {
      const int slot = bi >> 10;
#pragma unroll
      for (int i = 0; i < SV; ++i) if (i == slot) sv[i] = -sv[i];
    }
    if (tid == 0) {
      int found = -1;
      for (int j = 0; j < diff_cnt; ++j) if (diff[j] == bi) found = j;
      if (found >= 0) { diff[found] = diff[diff_cnt - 1]; diff_cnt -= 1; }
      else { diff[diff_cnt] = bi; diff_cnt += 1; }
    }
    __syncthreads();
  }

  const double lse_y = block_lse();

  const int dc_n = diff_cnt;
  for (int j = 0; j < dc_n; ++j) {
    const int d = diff[j];
    if ((d & (NT - 1)) == tid) {
      const int slot = d >> 10;
#pragma unroll
      for (int i = 0; i < SV; ++i) if (i == slot) sflip[j] = sv[i];
    }
  }
  if (tid < dc_n) sgn_sh[tid] = 1.0f - 2.0f * x[(size_t)b * DIM + diff[tid]];
  __syncthreads();

  double dsp = 0.0;
  {
    const int hh = tid;
    const float hxv = h_base[(size_t)b * HID + hh];
    double delta = 0.0;
    for (int j = 0; j < dc_n; ++j)
      delta += (double)sgn_sh[j] * (double)W[(size_t)diff[j] * HID + hh];
    if (dc_n > 0) {
      const double hx = (double)hxv;
      dsp += softplus_d(hx + delta) - softplus_d(hx);
    }
  }
  for (int o = 32; o; o >>= 1) dsp += __shfl_xor(dsp, o);
  if ((tid & 63) == 0) red_d[tid >> 6] = dsp;
  __syncthreads();

  if (tid == 0) {
    const double dsp_tot = tree16d(red_d);
    double dc = 0.0, ltilde = 0.0;
    for (int j = 0; j < dc_n; ++j) {
      dc += (double)sgn_sh[j] * (double)c[diff[j]];
      ltilde += 2.0 * (double)sflip[j];
    }
    double la = (dsp_tot + dc) + ltilde + (logZx - lse_y);
    if (la > 0.0) la = 0.0;
    const double p = exp(la);
    uint32_t ku0, ku1, o0, o1;
    tf2x32(0u, 42u, 0u, 16u, ku0, ku1);
    tf2x32(ku0, ku1, 0u, (uint32_t)b, o0, o1);
    const float ub = bits_to_unit_float(o0 ^ o1);
    accept_flag = (p >= (double)ub) ? 1 : 0;
  }
  __syncthreads();

  {
    const float4* xr = (const float4*)(x + (size_t)b * DIM);
    float4* orow = (float4*)(out + (size_t)b * DIM);
    for (int i = 0; i < DIM / 4 / NT; ++i)
      orow[i * NT + tid] = xr[i * NT + tid];
  }
  __syncthreads();
  if (accept_flag && tid < dc_n) {
    const int d = diff[tid];
    out[(size_t)b * DIM + d] = 1.0f - x[(size_t)b * DIM + d];
  }
}

// ---------------- launch ----------------
extern "C" void kernel_launch(void* const* d_in, const int* in_sizes, int n_in,
                              void* d_out, int out_size, void* d_ws, size_t ws_size,
                              hipStream_t stream) {
  const float* x      = (const float*)d_in[0];
  const float* W      = (const float*)d_in[1];
  const float* bh     = (const float*)d_in[2];
  const float* c      = (const float*)d_in[3];
  const int*   radius = (const int*)d_in[4];
  float* out = (float*)d_out;
  const size_t F = sizeof(float);

  if (ws_size < (size_t)2 * BSIZE * HID * F) return;   // proven ws >= 41.9 MB (R10)

  float* h_ws   = (float*)d_ws;
  float* sig_ws = h_ws + (size_t)BSIZE * HID;
  float* P      = out;   // d_out[0, 16M floats) dead until gemm2 writes s

  dim3 g1(HID / 128, BSIZE / 128, SPLITK);
  gemm_h_split_kernel<<<g1, 256, 0, stream>>>(x, W, P);

  reduce_h_sig_kernel<<<(BSIZE * HID / 4) / 256, 256, 0, stream>>>(P, bh, h_ws, sig_ws);

  dim3 g2(BSIZE / 128, DIM / 128);
  gemm2_sig128_kernel<<<g2, 256, 0, stream>>>(sig_ws, W, c, x, out);

  if (ws_size >= ((size_t)2 * BSIZE * HID + 2 * NBKT) * F) {
    // bound-filter path (tables after h/sig in ws; 8 KB)
    float* gminb = sig_ws + (size_t)BSIZE * HID;
    float* gmaxb = gminb + NBKT;
    fill_gbounds_kernel<<<NBKT / 256, 256, 0, stream>>>(gminb, gmaxb);
    row_kernel_f<<<BSIZE, 512, 0, stream>>>(x, W, c, radius, h_ws, out,
                                            gminb, gmaxb, out);
  } else {
    row_kernel_w<<<BSIZE, NT, 0, stream>>>(x, W, c, radius, h_ws, out, out);
  }
}

// Round 12
// 1405.666 us; speedup vs baseline: 2.2283x; 1.2332x over previous
//
#include <hip/hip_runtime.h>
#include <stdint.h>

#define BSIZE 1024
#define DIM   16384
#define HID   1024
#define SPLITK 8
#define KC     (DIM / SPLITK)       /* 2048 */
#define NT    1024                  /* fallback wide row kernel */
#define SV    (DIM / NT)
#define NBKT  1024                  /* gumbel bound buckets (top 10 mantissa bits) */

// ---------------- threefry2x32 (JAX-compatible, 20 rounds) ----------------
__device__ __forceinline__ void tf2x32(uint32_t k0, uint32_t k1,
                                       uint32_t x0, uint32_t x1,
                                       uint32_t& o0, uint32_t& o1) {
  const uint32_t ks2 = k0 ^ k1 ^ 0x1BD11BDAu;
#define TFR(r) { x0 += x1; x1 = (x1 << r) | (x1 >> (32 - r)); x1 ^= x0; }
  x0 += k0; x1 += k1;
  TFR(13) TFR(15) TFR(26) TFR(6)
  x0 += k1;  x1 += ks2 + 1u;
  TFR(17) TFR(29) TFR(16) TFR(24)
  x0 += ks2; x1 += k0 + 2u;
  TFR(13) TFR(15) TFR(26) TFR(6)
  x0 += k0;  x1 += k1 + 3u;
  TFR(17) TFR(29) TFR(16) TFR(24)
  x0 += k1;  x1 += ks2 + 4u;
  TFR(13) TFR(15) TFR(26) TFR(6)
  x0 += ks2; x1 += k0 + 5u;
#undef TFR
  o0 = x0; o1 = x1;
}

__device__ __forceinline__ float bits_to_unit_float(uint32_t bits) {
  return __uint_as_float((bits >> 9) | 0x3f800000u) - 1.0f;
}

__device__ __forceinline__ float bits_to_gumbel(uint32_t bits) {
  float u = bits_to_unit_float(bits);
  if (u == 0.0f) u = 1.1754943508222875e-38f;   // minval = finfo(f32).tiny
  float l1 = (float)log((double)u);
  float nl1 = -l1;
  float l2 = (float)log((double)nl1);
  return -l2;
}

__device__ __forceinline__ double softplus_d(double z) {
  return (z > 0.0) ? (z + log1p(exp(-z))) : log1p(exp(z));
}

// ------- K0a: per-bucket EXACT gumbel bounds (monotone in mantissa) -------
__global__ __launch_bounds__(256) void fill_gbounds_kernel(
    float* __restrict__ gminb, float* __restrict__ gmaxb) {
  const uint32_t i = blockIdx.x * 256 + threadIdx.x;   // [0, 1024)
  const uint32_t mlo = i << 13;
  const uint32_t mhi = mlo + 8191u;
  gminb[i] = bits_to_gumbel(mlo << 9);
  gmaxb[i] = bits_to_gumbel(mhi << 9);
}

// ------- K0b: stable descending-radius permutation (LPT schedule) -------
__global__ __launch_bounds__(1024) void sort_perm_kernel(
    const int* __restrict__ radius, int* __restrict__ perm) {
  __shared__ int rad[BSIZE];
  const int i = threadIdx.x;
  int r = radius[i];
  if (r < 0) r = 0;
  if (r > 15) r = 15;
  rad[i] = r;
  __syncthreads();
  int rank = 0;
  for (int j = 0; j < BSIZE; ++j) {
    const int rj = rad[j];
    rank += (rj > r) || (rj == r && j < i);
  }
  perm[rank] = i;
}

// ------- K1: split-K GEMM  P[s] = x[:, sKC:(s+1)KC] @ W[sKC:...]  (128x128) -------
__global__ __launch_bounds__(256) void gemm_h_split_kernel(
    const float* __restrict__ x, const float* __restrict__ W,
    float* __restrict__ P) {
  __shared__ float Al[32][128];
  __shared__ float Bl[32][128];
  const int tid = threadIdx.x;
  const int n0 = blockIdx.x * 128;
  const int m0 = blockIdx.y * 128;
  const int s  = blockIdx.z;
  const int arow = tid >> 1, akof = (tid & 1) * 16;
  const int brow = tid >> 3, bcol = (tid & 7) * 16;
  const int ty = tid >> 4, tx = tid & 15;

  float acc[8][8];
  for (int i = 0; i < 8; ++i)
    for (int j = 0; j < 8; ++j) acc[i][j] = 0.0f;

  for (int kt = 0; kt < KC / 32; ++kt) {
    const int k0 = s * KC + kt * 32;
    const float* ap = x + (size_t)(m0 + arow) * DIM + k0 + akof;
    float4 av0 = *(const float4*)(ap + 0);
    float4 av1 = *(const float4*)(ap + 4);
    float4 av2 = *(const float4*)(ap + 8);
    float4 av3 = *(const float4*)(ap + 12);
    const float* bp = W + (size_t)(k0 + brow) * HID + n0 + bcol;
    float4 bv0 = *(const float4*)(bp + 0);
    float4 bv1 = *(const float4*)(bp + 4);
    float4 bv2 = *(const float4*)(bp + 8);
    float4 bv3 = *(const float4*)(bp + 12);
    __syncthreads();
    {
      float ta[16] = {av0.x,av0.y,av0.z,av0.w, av1.x,av1.y,av1.z,av1.w,
                      av2.x,av2.y,av2.z,av2.w, av3.x,av3.y,av3.z,av3.w};
      for (int e = 0; e < 16; ++e) Al[akof + e][arow] = ta[e];
    }
    *(float4*)&Bl[brow][bcol + 0]  = bv0;
    *(float4*)&Bl[brow][bcol + 4]  = bv1;
    *(float4*)&Bl[brow][bcol + 8]  = bv2;
    *(float4*)&Bl[brow][bcol + 12] = bv3;
    __syncthreads();
#pragma unroll 4
    for (int k = 0; k < 32; ++k) {
      const float4 a0 = *(const float4*)&Al[k][ty * 8];
      const float4 a1 = *(const float4*)&Al[k][ty * 8 + 4];
      const float4 b0 = *(const float4*)&Bl[k][tx * 8];
      const float4 b1 = *(const float4*)&Bl[k][tx * 8 + 4];
      const float a[8]  = {a0.x,a0.y,a0.z,a0.w, a1.x,a1.y,a1.z,a1.w};
      const float bb[8] = {b0.x,b0.y,b0.z,b0.w, b1.x,b1.y,b1.z,b1.w};
      for (int i = 0; i < 8; ++i)
        for (int j = 0; j < 8; ++j)
          acc[i][j] = fmaf(a[i], bb[j], acc[i][j]);
    }
  }
  float* Cp = P + (size_t)s * (BSIZE * HID);
  for (int i = 0; i < 8; ++i) {
    const int gm = m0 + ty * 8 + i;
    float4 w0 = {acc[i][0], acc[i][1], acc[i][2], acc[i][3]};
    float4 w1 = {acc[i][4], acc[i][5], acc[i][6], acc[i][7]};
    *(float4*)(Cp + (size_t)gm * HID + n0 + tx * 8 + 0) = w0;
    *(float4*)(Cp + (size_t)gm * HID + n0 + tx * 8 + 4) = w1;
  }
}

// ------- K1r: h = sum_s P[s] + bh (fixed order) -> hbuf; sig (f64-exact) -------
__global__ __launch_bounds__(256) void reduce_h_sig_kernel(
    const float* __restrict__ P, const float* __restrict__ bh,
    float* __restrict__ hbuf, float* __restrict__ sig) {
  const int i = blockIdx.x * 256 + threadIdx.x;   // float4 idx, 262144 total
  float4 a = ((const float4*)P)[i];
  for (int s = 1; s < SPLITK; ++s) {
    float4 p = ((const float4*)P)[(size_t)s * (BSIZE * HID / 4) + i];
    a.x += p.x; a.y += p.y; a.z += p.z; a.w += p.w;
  }
  float4 bv = ((const float4*)bh)[i & (HID / 4 - 1)];
  float4 h;
  h.x = a.x + bv.x; h.y = a.y + bv.y; h.z = a.z + bv.z; h.w = a.w + bv.w;
  ((float4*)hbuf)[i] = h;
  float4 sg;
  sg.x = (float)(1.0 / (1.0 + exp(-(double)h.x)));
  sg.y = (float)(1.0 / (1.0 + exp(-(double)h.y)));
  sg.z = (float)(1.0 / (1.0 + exp(-(double)h.z)));
  sg.w = (float)(1.0 / (1.0 + exp(-(double)h.w)));
  ((float4*)sig)[i] = sg;
}

// -- K2s128: s = (1-2x)*(sig @ W^T + c)*0.5, 128x128 tiles --
__global__ __launch_bounds__(256) void gemm2_sig128_kernel(
    const float* __restrict__ sig_src, const float* __restrict__ W,
    const float* __restrict__ c, const float* __restrict__ x,
    float* __restrict__ s_dst) {
  __shared__ float Al[32][128];
  __shared__ float Bl[32][128];
  const int tid = threadIdx.x;
  const int m0 = blockIdx.x * 128;
  const int n0 = blockIdx.y * 128;
  const int row2 = tid >> 1, kof = (tid & 1) * 16;
  const int ty = tid >> 4, tx = tid & 15;

  float acc[8][8];
  for (int i = 0; i < 8; ++i)
    for (int j = 0; j < 8; ++j) acc[i][j] = 0.0f;

  for (int kt = 0; kt < HID / 32; ++kt) {
    const int k0 = kt * 32;
    const float* ap = sig_src + (size_t)(m0 + row2) * HID + k0 + kof;
    float4 av0 = *(const float4*)(ap + 0);
    float4 av1 = *(const float4*)(ap + 4);
    float4 av2 = *(const float4*)(ap + 8);
    float4 av3 = *(const float4*)(ap + 12);
    const float* bp = W + (size_t)(n0 + row2) * HID + k0 + kof;
    float4 bv0 = *(const float4*)(bp + 0);
    float4 bv1 = *(const float4*)(bp + 4);
    float4 bv2 = *(const float4*)(bp + 8);
    float4 bv3 = *(const float4*)(bp + 12);
    __syncthreads();
    {
      float ta[16] = {av0.x,av0.y,av0.z,av0.w, av1.x,av1.y,av1.z,av1.w,
                      av2.x,av2.y,av2.z,av2.w, av3.x,av3.y,av3.z,av3.w};
      float tb[16] = {bv0.x,bv0.y,bv0.z,bv0.w, bv1.x,bv1.y,bv1.z,bv1.w,
                      bv2.x,bv2.y,bv2.z,bv2.w, bv3.x,bv3.y,bv3.z,bv3.w};
      for (int e = 0; e < 16; ++e) { Al[kof + e][row2] = ta[e]; Bl[kof + e][row2] = tb[e]; }
    }
    __syncthreads();
#pragma unroll 4
    for (int k = 0; k < 32; ++k) {
      const float4 a0 = *(const float4*)&Al[k][ty * 8];
      const float4 a1 = *(const float4*)&Al[k][ty * 8 + 4];
      const float4 b0 = *(const float4*)&Bl[k][tx * 8];
      const float4 b1 = *(const float4*)&Bl[k][tx * 8 + 4];
      const float a[8]  = {a0.x,a0.y,a0.z,a0.w, a1.x,a1.y,a1.z,a1.w};
      const float bb[8] = {b0.x,b0.y,b0.z,b0.w, b1.x,b1.y,b1.z,b1.w};
      for (int i = 0; i < 8; ++i)
        for (int j = 0; j < 8; ++j)
          acc[i][j] = fmaf(a[i], bb[j], acc[i][j]);
    }
  }
  for (int i = 0; i < 8; ++i) {
    const int gm = m0 + ty * 8 + i;
    const size_t rowoff = (size_t)gm * DIM + n0 + tx * 8;
    for (int q = 0; q < 2; ++q) {
      float4 xv = *(const float4*)(x + rowoff + q * 4);
      float4 cv = *(const float4*)(c + n0 + tx * 8 + q * 4);
      float g0 = acc[i][q * 4 + 0] + cv.x;
      float g1 = acc[i][q * 4 + 1] + cv.y;
      float g2 = acc[i][q * 4 + 2] + cv.z;
      float g3 = acc[i][q * 4 + 3] + cv.w;
      float4 sv;
      sv.x = ((xv.x == 1.0f) ? -g0 : g0) * 0.5f;
      sv.y = ((xv.y == 1.0f) ? -g1 : g1) * 0.5f;
      sv.z = ((xv.z == 1.0f) ? -g2 : g2) * 0.5f;
      sv.w = ((xv.w == 1.0f) ? -g3 : g3) * 0.5f;
      *(float4*)(s_dst + rowoff + q * 4) = sv;
    }
  }
}

// ------- K3f: bound-filtered row kernel (R11) + single-threefry-pass
// (bits kept in registers) + LPT row permutation. Bit-identical selection. -------
__global__ __launch_bounds__(512) void row_kernel_f(
    const float* __restrict__ x, const float* __restrict__ W,
    const float* __restrict__ c, const int* __restrict__ radius,
    const float* __restrict__ h_base,   // + row*HID
    const float* __restrict__ s_base,   // + row*DIM
    const float* __restrict__ gminb, const float* __restrict__ gmaxb,
    const int* __restrict__ perm,
    float* __restrict__ out) {
  const int b = perm[blockIdx.x];       // LPT: longest radius first
  const int tid = threadIdx.x;

  __shared__ float  gmin_l[NBKT];
  __shared__ float  gmax_l[NBKT];
  __shared__ float  red_v[8];
  __shared__ int    red_i[8];
  __shared__ double red_d[8];
  __shared__ int    diff[16];
  __shared__ float  sgn_sh[16];
  __shared__ float  sflip[16];
  __shared__ int    diff_cnt;
  __shared__ int    accept_flag;

  if (tid == 0) diff_cnt = 0;
  gmin_l[tid]       = gminb[tid];
  gmin_l[tid + 512] = gminb[tid + 512];
  gmax_l[tid]       = gmaxb[tid];
  gmax_l[tid + 512] = gmaxb[tid + 512];

  float sv[32];
#pragma unroll
  for (int i = 0; i < 32; ++i)
    sv[i] = s_base[(size_t)b * DIM + tid + i * 512];
  __syncthreads();   // tables visible

  auto block_lse = [&]() -> double {
    float mloc = sv[0];
#pragma unroll
    for (int i = 1; i < 32; ++i) mloc = fmaxf(mloc, sv[i]);
    for (int o = 32; o; o >>= 1) mloc = fmaxf(mloc, __shfl_xor(mloc, o));
    if ((tid & 63) == 0) red_v[tid >> 6] = mloc;
    __syncthreads();
    const float m = fmaxf(fmaxf(fmaxf(red_v[0], red_v[1]), fmaxf(red_v[2], red_v[3])),
                          fmaxf(fmaxf(red_v[4], red_v[5]), fmaxf(red_v[6], red_v[7])));
    double ssum = 0.0;
#pragma unroll
    for (int i = 0; i < 32; ++i) ssum += exp((double)sv[i] - (double)m);
    for (int o = 32; o; o >>= 1) ssum += __shfl_xor(ssum, o);
    if ((tid & 63) == 0) red_d[tid >> 6] = ssum;
    __syncthreads();
    double tot = ((red_d[0] + red_d[1]) + (red_d[2] + red_d[3])) +
                 ((red_d[4] + red_d[5]) + (red_d[6] + red_d[7]));
    __syncthreads();
    return log(tot) + (double)m;
  };

  const double logZx = block_lse();

  int r = radius[b];
  if (r < 0) r = 0;
  if (r > 15) r = 15;
  const uint32_t jbase = (uint32_t)(b * DIM);

  for (int t = 0; t < r; ++t) {
    uint32_t kt0, kt1;
    tf2x32(0u, 42u, 0u, (uint32_t)t, kt0, kt1);   // fold_in(key(42), t)

    // ---- pass 1: generate bits ONCE (registers) + exact lower bound L ----
    uint32_t bb[32];
    float lbmax = -3.402823466e38f;
#pragma unroll
    for (int i = 0; i < 32; ++i) {
      const int d = tid + (i << 9);
      uint32_t o0, o1;
      tf2x32(kt0, kt1, 0u, jbase + (uint32_t)d, o0, o1);
      bb[i] = o0 ^ o1;
      lbmax = fmaxf(lbmax, gmin_l[bb[i] >> 22] + sv[i]);
    }
    for (int o = 32; o; o >>= 1) lbmax = fmaxf(lbmax, __shfl_xor(lbmax, o));
    if ((tid & 63) == 0) red_v[tid >> 6] = lbmax;
    __syncthreads();
    const float L = fmaxf(fmaxf(fmaxf(red_v[0], red_v[1]), fmaxf(red_v[2], red_v[3])),
                          fmaxf(fmaxf(red_v[4], red_v[5]), fmaxf(red_v[6], red_v[7])));
    __syncthreads();   // red_v free for winner reduce

    // ---- pass 2: exact eval only where upper bound can reach L ----
    float bestv = -3.402823466e38f;
    int   besti = 0x7fffffff;
#pragma unroll
    for (int i = 0; i < 32; ++i) {
      const int d = tid + (i << 9);
      const uint32_t bits = bb[i];
      if (gmax_l[bits >> 22] + sv[i] >= L) {
        const float val = bits_to_gumbel(bits) + sv[i];   // exact path
        if (val > bestv) { bestv = val; besti = d; }
      }
    }
    for (int o = 32; o; o >>= 1) {
      const float ov = __shfl_xor(bestv, o);
      const int   oi = __shfl_xor(besti, o);
      if (ov > bestv || (ov == bestv && oi < besti)) { bestv = ov; besti = oi; }
    }
    if ((tid & 63) == 0) { red_v[tid >> 6] = bestv; red_i[tid >> 6] = besti; }
    __syncthreads();
    float bv = red_v[0]; int bi = red_i[0];
    for (int w = 1; w < 8; ++w)
      if (red_v[w] > bv || (red_v[w] == bv && red_i[w] < bi)) { bv = red_v[w]; bi = red_i[w]; }
    if ((bi & 511) == tid) {
      const int slot = bi >> 9;
#pragma unroll
      for (int i = 0; i < 32; ++i) if (i == slot) sv[i] = -sv[i];
    }
    if (tid == 0) {
      int found = -1;
      for (int j = 0; j < diff_cnt; ++j) if (diff[j] == bi) found = j;
      if (found >= 0) { diff[found] = diff[diff_cnt - 1]; diff_cnt -= 1; }
      else { diff[diff_cnt] = bi; diff_cnt += 1; }
    }
    __syncthreads();
  }

  const double lse_y = block_lse();

  const int dc_n = diff_cnt;
  for (int j = 0; j < dc_n; ++j) {
    const int d = diff[j];
    if ((d & 511) == tid) {
      const int slot = d >> 9;
#pragma unroll
      for (int i = 0; i < 32; ++i) if (i == slot) sflip[j] = sv[i];
    }
  }
  if (tid < dc_n) sgn_sh[tid] = 1.0f - 2.0f * x[(size_t)b * DIM + diff[tid]];
  __syncthreads();

  double dsp = 0.0;
  for (int rep = 0; rep < 2; ++rep) {
    const int hh = tid + rep * 512;
    const float hxv = h_base[(size_t)b * HID + hh];
    double delta = 0.0;
    for (int j = 0; j < dc_n; ++j)
      delta += (double)sgn_sh[j] * (double)W[(size_t)diff[j] * HID + hh];
    if (dc_n > 0) {
      const double hx = (double)hxv;
      dsp += softplus_d(hx + delta) - softplus_d(hx);
    }
  }
  for (int o = 32; o; o >>= 1) dsp += __shfl_xor(dsp, o);
  if ((tid & 63) == 0) red_d[tid >> 6] = dsp;
  __syncthreads();

  if (tid == 0) {
    const double dsp_tot = ((red_d[0] + red_d[1]) + (red_d[2] + red_d[3])) +
                           ((red_d[4] + red_d[5]) + (red_d[6] + red_d[7]));
    double dc = 0.0, ltilde = 0.0;
    for (int j = 0; j < dc_n; ++j) {
      dc += (double)sgn_sh[j] * (double)c[diff[j]];
      ltilde += 2.0 * (double)sflip[j];
    }
    double la = (dsp_tot + dc) + ltilde + (logZx - lse_y);
    if (la > 0.0) la = 0.0;
    const double p = exp(la);
    uint32_t ku0, ku1, o0, o1;
    tf2x32(0u, 42u, 0u, 16u, ku0, ku1);          // fold_in(key(42), 16)
    tf2x32(ku0, ku1, 0u, (uint32_t)b, o0, o1);   // ctr (0, b)
    const float ub = bits_to_unit_float(o0 ^ o1);
    accept_flag = (p >= (double)ub) ? 1 : 0;
  }
  __syncthreads();

  {
    const float4* xr = (const float4*)(x + (size_t)b * DIM);
    float4* orow = (float4*)(out + (size_t)b * DIM);
    for (int i = 0; i < DIM / 4 / 512; ++i)
      orow[i * 512 + tid] = xr[i * 512 + tid];
  }
  __syncthreads();
  if (accept_flag && tid < dc_n) {
    const int d = diff[tid];
    out[(size_t)b * DIM + d] = 1.0f - x[(size_t)b * DIM + d];
  }
}

// ------- K3w (fallback): 1024-thread exact row scan (R9, proven) -------
__global__ __launch_bounds__(1024) void row_kernel_w(
    const float* __restrict__ x, const float* __restrict__ W,
    const float* __restrict__ c, const int* __restrict__ radius,
    const float* __restrict__ h_base, const float* __restrict__ s_base,
    float* __restrict__ out) {
  const int b = blockIdx.x;
  const int tid = threadIdx.x;

  __shared__ float  red_v[16];
  __shared__ int    red_i[16];
  __shared__ double red_d[16];
  __shared__ int    diff[16];
  __shared__ float  sgn_sh[16];
  __shared__ float  sflip[16];
  __shared__ int    diff_cnt;
  __shared__ int    accept_flag;

  if (tid == 0) diff_cnt = 0;

  float sv[SV];
#pragma unroll
  for (int i = 0; i < SV; ++i)
    sv[i] = s_base[(size_t)b * DIM + tid + i * NT];

  auto tree16f = [&](const float* v) -> float {
    return fmaxf(fmaxf(fmaxf(fmaxf(v[0],v[1]),fmaxf(v[2],v[3])),
                       fmaxf(fmaxf(v[4],v[5]),fmaxf(v[6],v[7]))),
                 fmaxf(fmaxf(fmaxf(v[8],v[9]),fmaxf(v[10],v[11])),
                       fmaxf(fmaxf(v[12],v[13]),fmaxf(v[14],v[15]))));
  };
  auto tree16d = [&](const double* v) -> double {
    return ((((v[0]+v[1])+(v[2]+v[3])) + ((v[4]+v[5])+(v[6]+v[7])))
          + (((v[8]+v[9])+(v[10]+v[11])) + ((v[12]+v[13])+(v[14]+v[15]))));
  };

  auto block_lse = [&]() -> double {
    float mloc = sv[0];
#pragma unroll
    for (int i = 1; i < SV; ++i) mloc = fmaxf(mloc, sv[i]);
    for (int o = 32; o; o >>= 1) mloc = fmaxf(mloc, __shfl_xor(mloc, o));
    if ((tid & 63) == 0) red_v[tid >> 6] = mloc;
    __syncthreads();
    const float m = tree16f(red_v);
    double ssum = 0.0;
#pragma unroll
    for (int i = 0; i < SV; ++i) ssum += exp((double)sv[i] - (double)m);
    for (int o = 32; o; o >>= 1) ssum += __shfl_xor(ssum, o);
    if ((tid & 63) == 0) red_d[tid >> 6] = ssum;
    __syncthreads();
    double tot = tree16d(red_d);
    __syncthreads();
    return log(tot) + (double)m;
  };

  const double logZx = block_lse();

  int r = radius[b];
  if (r < 0) r = 0;
  if (r > 15) r = 15;
  const uint32_t jbase = (uint32_t)(b * DIM);

  for (int t = 0; t < r; ++t) {
    uint32_t kt0, kt1;
    tf2x32(0u, 42u, 0u, (uint32_t)t, kt0, kt1);
    float bestv;
    int   besti;
    {
      uint32_t o0, o1;
      tf2x32(kt0, kt1, 0u, jbase + (uint32_t)tid, o0, o1);
      bestv = bits_to_gumbel(o0 ^ o1) + sv[0];
      besti = tid;
    }
#pragma unroll
    for (int i = 1; i < SV; ++i) {
      const int d = tid + i * NT;
      uint32_t o0, o1;
      tf2x32(kt0, kt1, 0u, jbase + (uint32_t)d, o0, o1);
      const float val = bits_to_gumbel(o0 ^ o1) + sv[i];
      if (val > bestv) { bestv = val; besti = d; }
    }
    for (int o = 32; o; o >>= 1) {
      const float ov = __shfl_xor(bestv, o);
      const int   oi = __shfl_xor(besti, o);
      if (ov > bestv || (ov == bestv && oi < besti)) { bestv = ov; besti = oi; }
    }
    if ((tid & 63) == 0) { red_v[tid >> 6] = bestv; red_i[tid >> 6] = besti; }
    __syncthreads();
    float bv = red_v[0]; int bi = red_i[0];
    for (int w = 1; w < 16; ++w)
      if (red_v[w] > bv || (red_v[w] == bv && red_i[w] < bi)) { bv = red_v[w]; bi = red_i[w]; }
    if ((bi & (NT - 1)) == tid) {
      const int slot = bi >> 10;
#pragma unroll
      for (int i = 0; i < SV; ++i) if (i == slot) sv[i] = -sv[i];
    }
    if (tid == 0) {
      int found = -1;
      for (int j = 0; j < diff_cnt; ++j) if (diff[j] == bi) found = j;
      if (found >= 0) { diff[found] = diff[diff_cnt - 1]; diff_cnt -= 1; }
      else { diff[diff_cnt] = bi; diff_cnt += 1; }
    }
    __syncthreads();
  }

  const double lse_y = block_lse();

  const int dc_n = diff_cnt;
  for (int j = 0; j < dc_n; ++j) {
    const int d = diff[j];
    if ((d & (NT - 1)) == tid) {
      const int slot = d >> 10;
#pragma unroll
      for (int i = 0; i < SV; ++i) if (i == slot) sflip[j] = sv[i];
    }
  }
  if (tid < dc_n) sgn_sh[tid] = 1.0f - 2.0f * x[(size_t)b * DIM + diff[tid]];
  __syncthreads();

  double dsp = 0.0;
  {
    const int hh = tid;
    const float hxv = h_base[(size_t)b * HID + hh];
    double delta = 0.0;
    for (int j = 0; j < dc_n; ++j)
      delta += (double)sgn_sh[j] * (double)W[(size_t)diff[j] * HID + hh];
    if (dc_n > 0) {
      const double hx = (double)hxv;
      dsp += softplus_d(hx + delta) - softplus_d(hx);
    }
  }
  for (int o = 32; o; o >>= 1) dsp += __shfl_xor(dsp, o);
  if ((tid & 63) == 0) red_d[tid >> 6] = dsp;
  __syncthreads();

  if (tid == 0) {
    const double dsp_tot = tree16d(red_d);
    double dc = 0.0, ltilde = 0.0;
    for (int j = 0; j < dc_n; ++j) {
      dc += (double)sgn_sh[j] * (double)c[diff[j]];
      ltilde += 2.0 * (double)sflip[j];
    }
    double la = (dsp_tot + dc) + ltilde + (logZx - lse_y);
    if (la > 0.0) la = 0.0;
    const double p = exp(la);
    uint32_t ku0, ku1, o0, o1;
    tf2x32(0u, 42u, 0u, 16u, ku0, ku1);
    tf2x32(ku0, ku1, 0u, (uint32_t)b, o0, o1);
    const float ub = bits_to_unit_float(o0 ^ o1);
    accept_flag = (p >= (double)ub) ? 1 : 0;
  }
  __syncthreads();

  {
    const float4* xr = (const float4*)(x + (size_t)b * DIM);
    float4* orow = (float4*)(out + (size_t)b * DIM);
    for (int i = 0; i < DIM / 4 / NT; ++i)
      orow[i * NT + tid] = xr[i * NT + tid];
  }
  __syncthreads();
  if (accept_flag && tid < dc_n) {
    const int d = diff[tid];
    out[(size_t)b * DIM + d] = 1.0f - x[(size_t)b * DIM + d];
  }
}

// ---------------- launch ----------------
extern "C" void kernel_launch(void* const* d_in, const int* in_sizes, int n_in,
                              void* d_out, int out_size, void* d_ws, size_t ws_size,
                              hipStream_t stream) {
  const float* x      = (const float*)d_in[0];
  const float* W      = (const float*)d_in[1];
  const float* bh     = (const float*)d_in[2];
  const float* c      = (const float*)d_in[3];
  const int*   radius = (const int*)d_in[4];
  float* out = (float*)d_out;
  const size_t F = sizeof(float);

  if (ws_size < (size_t)2 * BSIZE * HID * F) return;   // proven ws >= 41.9 MB (R10)

  float* h_ws   = (float*)d_ws;
  float* sig_ws = h_ws + (size_t)BSIZE * HID;
  float* P      = out;   // d_out[0, 16M floats) dead until gemm2 writes s

  dim3 g1(HID / 128, BSIZE / 128, SPLITK);
  gemm_h_split_kernel<<<g1, 256, 0, stream>>>(x, W, P);

  reduce_h_sig_kernel<<<(BSIZE * HID / 4) / 256, 256, 0, stream>>>(P, bh, h_ws, sig_ws);

  dim3 g2(BSIZE / 128, DIM / 128);
  gemm2_sig128_kernel<<<g2, 256, 0, stream>>>(sig_ws, W, c, x, out);

  if (ws_size >= ((size_t)2 * BSIZE * HID + 2 * NBKT + BSIZE) * F) {
    // bound-filter path: [h 4MB][sig 4MB][gmin 4KB][gmax 4KB][perm 4KB]
    float* gminb = sig_ws + (size_t)BSIZE * HID;
    float* gmaxb = gminb + NBKT;
    int*   perm  = (int*)(gmaxb + NBKT);
    fill_gbounds_kernel<<<NBKT / 256, 256, 0, stream>>>(gminb, gmaxb);
    sort_perm_kernel<<<1, BSIZE, 0, stream>>>(radius, perm);
    row_kernel_f<<<BSIZE, 512, 0, stream>>>(x, W, c, radius, h_ws, out,
                                            gminb, gmaxb, perm, out);
  } else {
    row_kernel_w<<<BSIZE, NT, 0, stream>>>(x, W, c, radius, h_ws, out, out);
  }
}